// Round 1
// baseline (549.027 us; speedup 1.0000x reference)
//
#include <hip/hip_runtime.h>
#include <hip/hip_bf16.h>

#define F_ 2048
#define C_ 64
#define NE (C_ * F_)   // 131072 elements per [64,2048] activation

// ---------------------------------------------------------------------------
// Kernel 1: x0_acc[c,o] += sum_{f in chunk} p[f] * W[c,f,o]
// grid (64 c, 2 o-tiles, 8 f-chunks), block 256. Thread handles 4 consecutive o
// via float4 loads (coalesced). p chunk staged in LDS (broadcast reads).
// ---------------------------------------------------------------------------
__global__ __launch_bounds__(256) void k_gemv(const float* __restrict__ p,
                                              const float* __restrict__ W,
                                              float* __restrict__ A0) {
    __shared__ float lp[256];
    const int c  = blockIdx.x;
    const int ot = blockIdx.y;
    const int ks = blockIdx.z;
    const int t  = threadIdx.x;
    const int f0 = ks * 256;
    lp[t] = p[f0 + t];
    __syncthreads();

    const int o = ot * 1024 + t * 4;
    const float* Wp = W + ((size_t)c << 22) + (size_t)f0 * F_ + o;
    float4 acc = make_float4(0.f, 0.f, 0.f, 0.f);
#pragma unroll 8
    for (int ff = 0; ff < 256; ++ff) {
        float4 w = *(const float4*)(Wp + (size_t)ff * F_);
        float pv = lp[ff];
        acc.x += pv * w.x; acc.y += pv * w.y;
        acc.z += pv * w.z; acc.w += pv * w.w;
    }
    float* dst = A0 + c * F_ + o;
    atomicAdd(dst + 0, acc.x);
    atomicAdd(dst + 1, acc.y);
    atomicAdd(dst + 2, acc.z);
    atomicAdd(dst + 3, acc.w);
}

// ---------------------------------------------------------------------------
// Kernel 2: h1 = x0 + recv_mask * sum_c(x0), where x0 = relu(A0 + child_b).
// One thread per feature o; the 64 node values live in registers (unrolled).
// ---------------------------------------------------------------------------
__global__ __launch_bounds__(256) void k_h1(const float* __restrict__ A0,
                                            const float* __restrict__ cb,
                                            float* __restrict__ H1) {
    const int o = blockIdx.x * 256 + threadIdx.x;
    float x[C_];
    float agg = 0.f;
#pragma unroll
    for (int c = 0; c < C_; ++c) {
        float v = fmaxf(A0[c * F_ + o] + cb[c * F_ + o], 0.f);
        x[c] = v;
        agg += v;
    }
#pragma unroll
    for (int c = 0; c < C_; ++c) {
        H1[c * F_ + o] = x[c] + (c > 0 ? agg : 0.f);
    }
}

// ---------------------------------------------------------------------------
// Kernel 3: f32 GEMM  A[c,n] += sum_{k in chunk} Hm[c,k] * W[k,n]
// M=64 (all rows per block), N-tile 256 (lane*4 float4), K-chunk 64 (split 32).
// h chunk in LDS, broadcast ds_read_b128; K-partials combined via atomicAdd.
// ---------------------------------------------------------------------------
__global__ __launch_bounds__(256) void k_gemm(const float* __restrict__ Hm,
                                              const float* __restrict__ W,
                                              float* __restrict__ A) {
    __shared__ float lh[C_ * 64];
    const int n0 = blockIdx.x * 256;
    const int k0 = blockIdx.y * 64;
    const int t  = threadIdx.x;

#pragma unroll
    for (int it = 0; it < 16; ++it) {
        int i = t + it * 256;
        lh[i] = Hm[(i >> 6) * F_ + k0 + (i & 63)];
    }
    __syncthreads();

    const int wave = t >> 6;
    const int lane = t & 63;
    const int cb   = wave * 16;     // this wave's 16 rows
    const int nn   = n0 + lane * 4; // this lane's 4 columns

    float4 acc[16];
#pragma unroll
    for (int i = 0; i < 16; ++i) acc[i] = make_float4(0.f, 0.f, 0.f, 0.f);

#pragma unroll
    for (int kq = 0; kq < 16; ++kq) {
        float4 w4[4];
#pragma unroll
        for (int j = 0; j < 4; ++j)
            w4[j] = *(const float4*)&W[(size_t)(k0 + kq * 4 + j) * F_ + nn];
#pragma unroll
        for (int cc = 0; cc < 16; ++cc) {
            float4 h4 = *(const float4*)&lh[(cb + cc) * 64 + kq * 4];
            acc[cc].x += h4.x * w4[0].x + h4.y * w4[1].x + h4.z * w4[2].x + h4.w * w4[3].x;
            acc[cc].y += h4.x * w4[0].y + h4.y * w4[1].y + h4.z * w4[2].y + h4.w * w4[3].y;
            acc[cc].z += h4.x * w4[0].z + h4.y * w4[1].z + h4.z * w4[2].z + h4.w * w4[3].z;
            acc[cc].w += h4.x * w4[0].w + h4.y * w4[1].w + h4.z * w4[2].w + h4.w * w4[3].w;
        }
    }

#pragma unroll
    for (int cc = 0; cc < 16; ++cc) {
        float* d = A + (cb + cc) * F_ + nn;
        atomicAdd(d + 0, acc[cc].x);
        atomicAdd(d + 1, acc[cc].y);
        atomicAdd(d + 2, acc[cc].z);
        atomicAdd(d + 3, acc[cc].w);
    }
}

// ---------------------------------------------------------------------------
// Kernel 4: elementwise T = relu(A + bias[o]), float4.
// ---------------------------------------------------------------------------
__global__ __launch_bounds__(256) void k_relu_bias(const float* __restrict__ A,
                                                   const float* __restrict__ b,
                                                   float* __restrict__ T) {
    const int i = (blockIdx.x * 256 + threadIdx.x) * 4;
    const int o = i & (F_ - 1);
    float4 a  = *(const float4*)(A + i);
    float4 bv = *(const float4*)(b + o);
    float4 r;
    r.x = fmaxf(a.x + bv.x, 0.f);
    r.y = fmaxf(a.y + bv.y, 0.f);
    r.z = fmaxf(a.z + bv.z, 0.f);
    r.w = fmaxf(a.w + bv.w, 0.f);
    *(float4*)(T + i) = r;
}

// ---------------------------------------------------------------------------
// Kernel 5: y = relu(A + bias); BatchNorm over nodes; H = xn + mask*sum_c(xn)
// (feeds GIN layer 2). One thread per feature o, node values in registers.
// ---------------------------------------------------------------------------
__global__ __launch_bounds__(256) void k_bnh(const float* __restrict__ A,
                                             const float* __restrict__ bias,
                                             const float* __restrict__ g,
                                             const float* __restrict__ beta,
                                             float* __restrict__ H) {
    const int o = blockIdx.x * 256 + threadIdx.x;
    const float b  = bias[o];
    const float gg = g[o];
    const float bb = beta[o];
    float y[C_];
    float s = 0.f, s2 = 0.f;
#pragma unroll
    for (int c = 0; c < C_; ++c) {
        float v = fmaxf(A[c * F_ + o] + b, 0.f);
        y[c] = v;
        s += v;
        s2 += v * v;
    }
    const float m   = s * (1.f / C_);
    const float var = s2 * (1.f / C_) - m * m;
    const float inv = gg / sqrtf(var + 1e-5f);
    float agg = 0.f;
#pragma unroll
    for (int c = 0; c < C_; ++c) {
        float xn = (y[c] - m) * inv + bb;
        y[c] = xn;
        agg += xn;
    }
#pragma unroll
    for (int c = 0; c < C_; ++c) {
        H[c * F_ + o] = y[c] + (c > 0 ? agg : 0.f);
    }
}

// ---------------------------------------------------------------------------
// Kernel 6: final BN: out = g*(relu(A+bias)-m)/sqrt(v+eps)+beta (no agg).
// ---------------------------------------------------------------------------
__global__ __launch_bounds__(256) void k_bn_out(const float* __restrict__ A,
                                                const float* __restrict__ bias,
                                                const float* __restrict__ g,
                                                const float* __restrict__ beta,
                                                float* __restrict__ out) {
    const int o = blockIdx.x * 256 + threadIdx.x;
    const float b  = bias[o];
    const float gg = g[o];
    const float bb = beta[o];
    float y[C_];
    float s = 0.f, s2 = 0.f;
#pragma unroll
    for (int c = 0; c < C_; ++c) {
        float v = fmaxf(A[c * F_ + o] + b, 0.f);
        y[c] = v;
        s += v;
        s2 += v * v;
    }
    const float m   = s * (1.f / C_);
    const float var = s2 * (1.f / C_) - m * m;
    const float inv = gg / sqrtf(var + 1e-5f);
#pragma unroll
    for (int c = 0; c < C_; ++c) {
        out[c * F_ + o] = (y[c] - m) * inv + bb;
    }
}

extern "C" void kernel_launch(void* const* d_in, const int* in_sizes, int n_in,
                              void* d_out, int out_size, void* d_ws, size_t ws_size,
                              hipStream_t stream) {
    const float* p   = (const float*)d_in[0];
    const float* cW  = (const float*)d_in[1];
    const float* cb  = (const float*)d_in[2];
    const float* W1a = (const float*)d_in[3];
    const float* b1a = (const float*)d_in[4];
    const float* W1b = (const float*)d_in[5];
    const float* b1b = (const float*)d_in[6];
    const float* g1  = (const float*)d_in[7];
    const float* be1 = (const float*)d_in[8];
    const float* W2a = (const float*)d_in[9];
    const float* b2a = (const float*)d_in[10];
    const float* W2b = (const float*)d_in[11];
    const float* b2b = (const float*)d_in[12];
    const float* g2  = (const float*)d_in[13];
    const float* be2 = (const float*)d_in[14];
    float* out = (float*)d_out;
    float* ws  = (float*)d_ws;

    float* A0 = ws + 0 * NE;   // accumulators (zeroed each call)
    float* A1 = ws + 1 * NE;
    float* A2 = ws + 2 * NE;
    float* A3 = ws + 3 * NE;
    float* A4 = ws + 4 * NE;
    float* H1 = ws + 5 * NE;   // activations
    float* T1 = ws + 6 * NE;
    float* H2 = ws + 7 * NE;
    float* T2 = ws + 8 * NE;

    hipMemsetAsync(ws, 0, (size_t)5 * NE * sizeof(float), stream);

    // child MLP: x0_acc = p @ child_W   (the 1.07 GB streaming read)
    k_gemv<<<dim3(64, 2, 8), 256, 0, stream>>>(p, cW, A0);
    // h1 = relu(x0_acc + child_b) + GIN aggregate
    k_h1<<<8, 256, 0, stream>>>(A0, cb, H1);
    // GIN 1
    k_gemm<<<dim3(8, 32), 256, 0, stream>>>(H1, W1a, A1);
    k_relu_bias<<<128, 256, 0, stream>>>(A1, b1a, T1);
    k_gemm<<<dim3(8, 32), 256, 0, stream>>>(T1, W1b, A2);
    // relu + BN1 + GIN-2 aggregate
    k_bnh<<<8, 256, 0, stream>>>(A2, b1b, g1, be1, H2);
    // GIN 2
    k_gemm<<<dim3(8, 32), 256, 0, stream>>>(H2, W2a, A3);
    k_relu_bias<<<128, 256, 0, stream>>>(A3, b2a, T2);
    k_gemm<<<dim3(8, 32), 256, 0, stream>>>(T2, W2b, A4);
    // relu + BN2 -> output
    k_bn_out<<<8, 256, 0, stream>>>(A4, b2b, g2, be2, out);
}

// Round 2
// 370.568 us; speedup vs baseline: 1.4816x; 1.4816x over previous
//
#include <hip/hip_runtime.h>
#include <hip/hip_bf16.h>

#define F_ 2048
#define C_ 64
#define NE (C_ * F_)   // 131072 elements per [64,2048] activation
#define GEMM_KS 16     // k-splits per GEMM
#define GEMV_KS 8      // f-splits in the child-MLP gemv

// ---------------------------------------------------------------------------
// Kernel 1: P0[ks][c][o] = sum_{f in chunk ks} p[f] * W[c,f,o]
// grid (64 c, 2 o-tiles, 8 f-chunks), block 256. Thread: 4 consecutive o via
// float4 (coalesced). Plain stores to partials — no atomics.
// ---------------------------------------------------------------------------
__global__ __launch_bounds__(256) void k_gemv(const float* __restrict__ p,
                                              const float* __restrict__ W,
                                              float* __restrict__ P0) {
    __shared__ float lp[256];
    const int c  = blockIdx.x;
    const int ot = blockIdx.y;
    const int ks = blockIdx.z;
    const int t  = threadIdx.x;
    const int f0 = ks * 256;
    lp[t] = p[f0 + t];
    __syncthreads();

    const int o = ot * 1024 + t * 4;
    const float* Wp = W + ((size_t)c << 22) + (size_t)f0 * F_ + o;
    float4 acc = make_float4(0.f, 0.f, 0.f, 0.f);
#pragma unroll 8
    for (int ff = 0; ff < 256; ++ff) {
        float4 w = *(const float4*)(Wp + (size_t)ff * F_);
        float pv = lp[ff];
        acc.x += pv * w.x; acc.y += pv * w.y;
        acc.z += pv * w.z; acc.w += pv * w.w;
    }
    *(float4*)(P0 + (size_t)ks * NE + c * F_ + o) = acc;
}

// ---------------------------------------------------------------------------
// Kernel 2: reduce 8 gemv partials + child_b -> relu -> GIN aggregate -> H1.
// Block owns a [64 c][64 o] tile. Thread t: c = t>>2, 16 consecutive o.
// ---------------------------------------------------------------------------
__global__ __launch_bounds__(256) void k_h1(const float* __restrict__ P0,
                                            const float* __restrict__ cb,
                                            float* __restrict__ H1) {
    __shared__ float xs[64 * 68];       // padded stride 68 (16B-aligned rows)
    __shared__ float gsum[256];
    __shared__ float aggL[64];
    const int t  = threadIdx.x;
    const int o0 = blockIdx.x * 64;
    const int c  = t >> 2;
    const int oq = t & 3;
    const int ob = o0 + oq * 16;

    float4 x4[4];
#pragma unroll
    for (int j = 0; j < 4; ++j)
        x4[j] = *(const float4*)(cb + c * F_ + ob + j * 4);
#pragma unroll
    for (int ps = 0; ps < GEMV_KS; ++ps) {
        const float* src = P0 + (size_t)ps * NE + c * F_ + ob;
#pragma unroll
        for (int j = 0; j < 4; ++j) {
            float4 v = *(const float4*)(src + j * 4);
            x4[j].x += v.x; x4[j].y += v.y; x4[j].z += v.z; x4[j].w += v.w;
        }
    }
#pragma unroll
    for (int j = 0; j < 4; ++j) {
        x4[j].x = fmaxf(x4[j].x, 0.f);
        x4[j].y = fmaxf(x4[j].y, 0.f);
        x4[j].z = fmaxf(x4[j].z, 0.f);
        x4[j].w = fmaxf(x4[j].w, 0.f);
        *(float4*)&xs[c * 68 + oq * 16 + j * 4] = x4[j];
    }
    __syncthreads();

    // per-o sum over c: 4 groups of 16 c each
    {
        const int g = t >> 6, o = t & 63;
        float s = 0.f;
#pragma unroll
        for (int i = 0; i < 16; ++i) s += xs[(g * 16 + i) * 68 + o];
        gsum[g * 64 + o] = s;
    }
    __syncthreads();
    if (t < 64) aggL[t] = gsum[t] + gsum[64 + t] + gsum[128 + t] + gsum[192 + t];
    __syncthreads();

#pragma unroll
    for (int j = 0; j < 4; ++j) {
        float4 a = *(const float4*)&aggL[oq * 16 + j * 4];
        float4 r = x4[j];
        if (c > 0) { r.x += a.x; r.y += a.y; r.z += a.z; r.w += a.w; }
        *(float4*)(H1 + c * F_ + ob + j * 4) = r;
    }
}

// ---------------------------------------------------------------------------
// Kernel 3: f32 GEMM partials  P[ks][c][n] = sum_{k in chunk} Hm[c,k]*W[k,n]
// grid (16 n-tiles of 128, 16 k-splits of 128). H chunk [64][128] in LDS
// (broadcast b128 reads). Wave owns 16 rows, lane owns 2 cols. Plain stores.
// ---------------------------------------------------------------------------
__global__ __launch_bounds__(256) void k_gemm(const float* __restrict__ Hm,
                                              const float* __restrict__ W,
                                              float* __restrict__ P) {
    __shared__ float lh[C_ * 128];
    const int n0 = blockIdx.x * 128;
    const int k0 = blockIdx.y * 128;
    const int t  = threadIdx.x;

#pragma unroll
    for (int it = 0; it < 8; ++it) {
        int i4 = t + it * 256;
        int e  = i4 * 4;
        int c  = e >> 7;
        int k  = e & 127;
        *(float4*)&lh[e] = *(const float4*)&Hm[c * F_ + k0 + k];
    }
    __syncthreads();

    const int wave = t >> 6;
    const int lane = t & 63;
    const int cb   = wave * 16;
    const int nn   = n0 + lane * 2;

    float2 acc[16];
#pragma unroll
    for (int i = 0; i < 16; ++i) acc[i] = make_float2(0.f, 0.f);

#pragma unroll 4
    for (int kq = 0; kq < 32; ++kq) {
        float2 w2[4];
#pragma unroll
        for (int j = 0; j < 4; ++j)
            w2[j] = *(const float2*)&W[(size_t)(k0 + kq * 4 + j) * F_ + nn];
#pragma unroll
        for (int cc = 0; cc < 16; ++cc) {
            float4 h4 = *(const float4*)&lh[(cb + cc) * 128 + kq * 4];
            acc[cc].x += h4.x * w2[0].x + h4.y * w2[1].x + h4.z * w2[2].x + h4.w * w2[3].x;
            acc[cc].y += h4.x * w2[0].y + h4.y * w2[1].y + h4.z * w2[2].y + h4.w * w2[3].y;
        }
    }

    float* dst = P + (size_t)blockIdx.y * NE + cb * F_ + nn;
#pragma unroll
    for (int cc = 0; cc < 16; ++cc)
        *(float2*)(dst + cc * F_) = acc[cc];
}

// ---------------------------------------------------------------------------
// Kernel 4: elementwise T = relu(sum_p P[p] + bias[o]), float4, big grid.
// ---------------------------------------------------------------------------
__global__ __launch_bounds__(256) void k_act(const float* __restrict__ P,
                                             const float* __restrict__ b,
                                             float* __restrict__ T) {
    const int e = (blockIdx.x * 256 + threadIdx.x) * 4;
    const int o = e & (F_ - 1);
    float4 a = *(const float4*)(b + o);
#pragma unroll
    for (int ps = 0; ps < GEMM_KS; ++ps) {
        float4 v = *(const float4*)(P + (size_t)ps * NE + e);
        a.x += v.x; a.y += v.y; a.z += v.z; a.w += v.w;
    }
    a.x = fmaxf(a.x, 0.f); a.y = fmaxf(a.y, 0.f);
    a.z = fmaxf(a.z, 0.f); a.w = fmaxf(a.w, 0.f);
    *(float4*)(T + e) = a;
}

// ---------------------------------------------------------------------------
// Kernel 5: reduce partials + bias -> relu -> BatchNorm -> (+ GIN-2 agg) -> H
// sum_c(BN(x)) == 64*beta exactly, so no second reduction pass is needed.
// ---------------------------------------------------------------------------
__global__ __launch_bounds__(256) void k_bnh(const float* __restrict__ P,
                                             const float* __restrict__ bias,
                                             const float* __restrict__ g,
                                             const float* __restrict__ beta,
                                             float* __restrict__ H) {
    __shared__ float xs[64 * 68];
    __shared__ float gs[256];
    __shared__ float gs2[256];
    __shared__ float mL[64];
    __shared__ float rL[64];
    const int t  = threadIdx.x;
    const int o0 = blockIdx.x * 64;
    const int c  = t >> 2;
    const int oq = t & 3;
    const int ob = o0 + oq * 16;

    float4 x4[4];
#pragma unroll
    for (int j = 0; j < 4; ++j)
        x4[j] = *(const float4*)(bias + ob + j * 4);
#pragma unroll
    for (int ps = 0; ps < GEMM_KS; ++ps) {
        const float* src = P + (size_t)ps * NE + c * F_ + ob;
#pragma unroll
        for (int j = 0; j < 4; ++j) {
            float4 v = *(const float4*)(src + j * 4);
            x4[j].x += v.x; x4[j].y += v.y; x4[j].z += v.z; x4[j].w += v.w;
        }
    }
#pragma unroll
    for (int j = 0; j < 4; ++j) {
        x4[j].x = fmaxf(x4[j].x, 0.f);
        x4[j].y = fmaxf(x4[j].y, 0.f);
        x4[j].z = fmaxf(x4[j].z, 0.f);
        x4[j].w = fmaxf(x4[j].w, 0.f);
        *(float4*)&xs[c * 68 + oq * 16 + j * 4] = x4[j];
    }
    __syncthreads();

    {
        const int gg = t >> 6, o = t & 63;
        float s = 0.f, s2 = 0.f;
#pragma unroll
        for (int i = 0; i < 16; ++i) {
            float v = xs[(gg * 16 + i) * 68 + o];
            s += v; s2 += v * v;
        }
        gs[gg * 64 + o] = s;
        gs2[gg * 64 + o] = s2;
    }
    __syncthreads();
    if (t < 64) {
        float s  = gs[t] + gs[64 + t] + gs[128 + t] + gs[192 + t];
        float s2 = gs2[t] + gs2[64 + t] + gs2[128 + t] + gs2[192 + t];
        float m  = s * (1.f / C_);
        float var = s2 * (1.f / C_) - m * m;
        mL[t] = m;
        rL[t] = 1.f / sqrtf(var + 1e-5f);
    }
    __syncthreads();

#pragma unroll
    for (int j = 0; j < 4; ++j) {
        float4 m4 = *(const float4*)&mL[oq * 16 + j * 4];
        float4 r4 = *(const float4*)&rL[oq * 16 + j * 4];
        float4 g4 = *(const float4*)(g + ob + j * 4);
        float4 b4 = *(const float4*)(beta + ob + j * 4);
        float4 r;
        r.x = (x4[j].x - m4.x) * r4.x * g4.x + b4.x;
        r.y = (x4[j].y - m4.y) * r4.y * g4.y + b4.y;
        r.z = (x4[j].z - m4.z) * r4.z * g4.z + b4.z;
        r.w = (x4[j].w - m4.w) * r4.w * g4.w + b4.w;
        if (c > 0) {   // GIN-2 aggregate: sum_c xn = 64*beta exactly
            r.x += C_ * b4.x; r.y += C_ * b4.y;
            r.z += C_ * b4.z; r.w += C_ * b4.w;
        }
        *(float4*)(H + c * F_ + ob + j * 4) = r;
    }
}

// ---------------------------------------------------------------------------
// Kernel 6: reduce partials + bias -> relu -> BatchNorm -> out (no agg).
// ---------------------------------------------------------------------------
__global__ __launch_bounds__(256) void k_bn_out(const float* __restrict__ P,
                                                const float* __restrict__ bias,
                                                const float* __restrict__ g,
                                                const float* __restrict__ beta,
                                                float* __restrict__ out) {
    __shared__ float xs[64 * 68];
    __shared__ float gs[256];
    __shared__ float gs2[256];
    __shared__ float mL[64];
    __shared__ float rL[64];
    const int t  = threadIdx.x;
    const int o0 = blockIdx.x * 64;
    const int c  = t >> 2;
    const int oq = t & 3;
    const int ob = o0 + oq * 16;

    float4 x4[4];
#pragma unroll
    for (int j = 0; j < 4; ++j)
        x4[j] = *(const float4*)(bias + ob + j * 4);
#pragma unroll
    for (int ps = 0; ps < GEMM_KS; ++ps) {
        const float* src = P + (size_t)ps * NE + c * F_ + ob;
#pragma unroll
        for (int j = 0; j < 4; ++j) {
            float4 v = *(const float4*)(src + j * 4);
            x4[j].x += v.x; x4[j].y += v.y; x4[j].z += v.z; x4[j].w += v.w;
        }
    }
#pragma unroll
    for (int j = 0; j < 4; ++j) {
        x4[j].x = fmaxf(x4[j].x, 0.f);
        x4[j].y = fmaxf(x4[j].y, 0.f);
        x4[j].z = fmaxf(x4[j].z, 0.f);
        x4[j].w = fmaxf(x4[j].w, 0.f);
        *(float4*)&xs[c * 68 + oq * 16 + j * 4] = x4[j];
    }
    __syncthreads();

    {
        const int gg = t >> 6, o = t & 63;
        float s = 0.f, s2 = 0.f;
#pragma unroll
        for (int i = 0; i < 16; ++i) {
            float v = xs[(gg * 16 + i) * 68 + o];
            s += v; s2 += v * v;
        }
        gs[gg * 64 + o] = s;
        gs2[gg * 64 + o] = s2;
    }
    __syncthreads();
    if (t < 64) {
        float s  = gs[t] + gs[64 + t] + gs[128 + t] + gs[192 + t];
        float s2 = gs2[t] + gs2[64 + t] + gs2[128 + t] + gs2[192 + t];
        float m  = s * (1.f / C_);
        float var = s2 * (1.f / C_) - m * m;
        mL[t] = m;
        rL[t] = 1.f / sqrtf(var + 1e-5f);
    }
    __syncthreads();

#pragma unroll
    for (int j = 0; j < 4; ++j) {
        float4 m4 = *(const float4*)&mL[oq * 16 + j * 4];
        float4 r4 = *(const float4*)&rL[oq * 16 + j * 4];
        float4 g4 = *(const float4*)(g + ob + j * 4);
        float4 b4 = *(const float4*)(beta + ob + j * 4);
        float4 r;
        r.x = (x4[j].x - m4.x) * r4.x * g4.x + b4.x;
        r.y = (x4[j].y - m4.y) * r4.y * g4.y + b4.y;
        r.z = (x4[j].z - m4.z) * r4.z * g4.z + b4.z;
        r.w = (x4[j].w - m4.w) * r4.w * g4.w + b4.w;
        *(float4*)(out + c * F_ + ob + j * 4) = r;
    }
}

extern "C" void kernel_launch(void* const* d_in, const int* in_sizes, int n_in,
                              void* d_out, int out_size, void* d_ws, size_t ws_size,
                              hipStream_t stream) {
    const float* p   = (const float*)d_in[0];
    const float* cW  = (const float*)d_in[1];
    const float* cb  = (const float*)d_in[2];
    const float* W1a = (const float*)d_in[3];
    const float* b1a = (const float*)d_in[4];
    const float* W1b = (const float*)d_in[5];
    const float* b1b = (const float*)d_in[6];
    const float* g1  = (const float*)d_in[7];
    const float* be1 = (const float*)d_in[8];
    const float* W2a = (const float*)d_in[9];
    const float* b2a = (const float*)d_in[10];
    const float* W2b = (const float*)d_in[11];
    const float* b2b = (const float*)d_in[12];
    const float* g2  = (const float*)d_in[13];
    const float* be2 = (const float*)d_in[14];
    float* out = (float*)d_out;
    float* ws  = (float*)d_ws;

    float* P0 = ws;                         // [8][64][2048]
    float* PA = P0 + (size_t)GEMV_KS * NE;  // [16][64][2048]
    float* PB = PA + (size_t)GEMM_KS * NE;  // [16][64][2048]
    float* H1 = PB + (size_t)GEMM_KS * NE;
    float* T1 = H1 + NE;
    float* H2 = T1 + NE;
    float* T2 = H2 + NE;

    // child MLP partials (the 1.07 GB streaming read)
    k_gemv<<<dim3(64, 2, GEMV_KS), 256, 0, stream>>>(p, cW, P0);
    // reduce + relu + GIN-1 aggregate
    k_h1<<<32, 256, 0, stream>>>(P0, cb, H1);
    // GIN 1
    k_gemm<<<dim3(16, GEMM_KS), 256, 0, stream>>>(H1, W1a, PA);
    k_act<<<128, 256, 0, stream>>>(PA, b1a, T1);
    k_gemm<<<dim3(16, GEMM_KS), 256, 0, stream>>>(T1, W1b, PB);
    // relu + BN1 + GIN-2 aggregate
    k_bnh<<<32, 256, 0, stream>>>(PB, b1b, g1, be1, H2);
    // GIN 2
    k_gemm<<<dim3(16, GEMM_KS), 256, 0, stream>>>(H2, W2a, PA);
    k_act<<<128, 256, 0, stream>>>(PA, b2a, T2);
    k_gemm<<<dim3(16, GEMM_KS), 256, 0, stream>>>(T2, W2b, PB);
    // relu + BN2 -> output
    k_bn_out<<<32, 256, 0, stream>>>(PB, b2b, g2, be2, out);
}

// Round 4
// 329.395 us; speedup vs baseline: 1.6668x; 1.1250x over previous
//
#include <hip/hip_runtime.h>
#include <hip/hip_bf16.h>

#define F_ 2048
#define C_ 64
#define NE (C_ * F_)   // 131072 elements per [64,2048] activation
#define GEMM_KS 16     // k-splits per GEMM (k-chunk = 128)
#define GEMV_KS 8      // f-splits in the child-MLP gemv

// ---------------------------------------------------------------------------
// Kernel 1: P0[ks][c][o] = sum_{f in chunk ks} p[f] * W[c,f,o]
// grid (64 c, 2 o-tiles, 8 f-chunks), block 256. Thread: 4 consecutive o via
// float4 (coalesced). Plain stores to partials — no atomics.
// ---------------------------------------------------------------------------
__global__ __launch_bounds__(256) void k_gemv(const float* __restrict__ p,
                                              const float* __restrict__ W,
                                              float* __restrict__ P0) {
    __shared__ float lp[256];
    const int c  = blockIdx.x;
    const int ot = blockIdx.y;
    const int ks = blockIdx.z;
    const int t  = threadIdx.x;
    const int f0 = ks * 256;
    lp[t] = p[f0 + t];
    __syncthreads();

    const int o = ot * 1024 + t * 4;
    const float* Wp = W + ((size_t)c << 22) + (size_t)f0 * F_ + o;
    float4 acc = make_float4(0.f, 0.f, 0.f, 0.f);
#pragma unroll 8
    for (int ff = 0; ff < 256; ++ff) {
        float4 w = *(const float4*)(Wp + (size_t)ff * F_);
        float pv = lp[ff];
        acc.x += pv * w.x; acc.y += pv * w.y;
        acc.z += pv * w.z; acc.w += pv * w.w;
    }
    *(float4*)(P0 + (size_t)ks * NE + c * F_ + o) = acc;
}

// ---------------------------------------------------------------------------
// Kernel 2: reduce 8 gemv partials + child_b -> relu -> GIN-1 agg -> H1.
// Block owns [64 c][16 o]; grid 128 so all CUs are active.
// Thread t: c = t>>2, 4 consecutive o (float4).
// ---------------------------------------------------------------------------
__global__ __launch_bounds__(256) void k_h1(const float* __restrict__ P0,
                                            const float* __restrict__ cb,
                                            float* __restrict__ H1) {
    __shared__ float xs[64 * 20];   // [c][o] stride 20
    __shared__ float gs[64];
    __shared__ float aggL[16];
    const int t  = threadIdx.x;
    const int o0 = blockIdx.x * 16;
    const int c  = t >> 2;
    const int oq = (t & 3) * 4;

    float4 x = *(const float4*)(cb + c * F_ + o0 + oq);
#pragma unroll
    for (int ps = 0; ps < GEMV_KS; ++ps) {
        float4 v = *(const float4*)(P0 + (size_t)ps * NE + c * F_ + o0 + oq);
        x.x += v.x; x.y += v.y; x.z += v.z; x.w += v.w;
    }
    x.x = fmaxf(x.x, 0.f); x.y = fmaxf(x.y, 0.f);
    x.z = fmaxf(x.z, 0.f); x.w = fmaxf(x.w, 0.f);
    xs[c * 20 + oq + 0] = x.x;
    xs[c * 20 + oq + 1] = x.y;
    xs[c * 20 + oq + 2] = x.z;
    xs[c * 20 + oq + 3] = x.w;
    __syncthreads();

    if (t < 64) {                    // stage 1: 4 groups of 16 c
        const int o = t & 15, cg = t >> 4;
        float s = 0.f;
#pragma unroll
        for (int i = 0; i < 16; ++i) s += xs[(cg * 16 + i) * 20 + o];
        gs[cg * 16 + o] = s;
    }
    __syncthreads();
    if (t < 16) aggL[t] = gs[t] + gs[16 + t] + gs[32 + t] + gs[48 + t];
    __syncthreads();

    float4 r = x;
    if (c > 0) {
        r.x += aggL[oq + 0]; r.y += aggL[oq + 1];
        r.z += aggL[oq + 2]; r.w += aggL[oq + 3];
    }
    *(float4*)(H1 + c * F_ + o0 + oq) = r;
}

// ---------------------------------------------------------------------------
// Kernel 3: f32 GEMM partials  P[ks][c][n] = sum_{k in chunk} Hm[c,k]*W[k,n]
// grid (32 n-tiles of 64, 16 k-chunks of 128) = 512 blocks (2/CU, 8 waves/CU).
// H chunk [64][128] in LDS (8 staging iters = 8192 floats — FULL panel).
// Wave: 16 rows; lane: 1 col.
// ---------------------------------------------------------------------------
__global__ __launch_bounds__(256) void k_gemm(const float* __restrict__ Hm,
                                              const float* __restrict__ W,
                                              float* __restrict__ P) {
    __shared__ float lh[C_ * 128];   // 32 KB
    const int n0 = blockIdx.x * 64;
    const int k0 = blockIdx.y * 128;
    const int t  = threadIdx.x;

#pragma unroll
    for (int it = 0; it < 8; ++it) {          // 8 * 256 * 4 = 8192 floats
        int e = (t + it * 256) * 4;
        int c = e >> 7;
        int k = e & 127;
        *(float4*)&lh[e] = *(const float4*)&Hm[c * F_ + k0 + k];
    }
    __syncthreads();

    const int wave = t >> 6;
    const int lane = t & 63;
    const int rb   = wave * 16;
    const int col  = n0 + lane;

    float acc[16];
#pragma unroll
    for (int i = 0; i < 16; ++i) acc[i] = 0.f;

#pragma unroll 4
    for (int kq = 0; kq < 32; ++kq) {
        float w[4];
#pragma unroll
        for (int j = 0; j < 4; ++j)
            w[j] = W[(size_t)(k0 + kq * 4 + j) * F_ + col];
#pragma unroll
        for (int r = 0; r < 16; ++r) {
            float4 h4 = *(const float4*)&lh[(rb + r) * 128 + kq * 4];
            acc[r] += h4.x * w[0] + h4.y * w[1] + h4.z * w[2] + h4.w * w[3];
        }
    }

    float* dst = P + (size_t)blockIdx.y * NE + rb * F_ + col;
#pragma unroll
    for (int r = 0; r < 16; ++r)
        dst[r * F_] = acc[r];
}

// ---------------------------------------------------------------------------
// Kernel 4: elementwise T = relu(sum_p P[p] + bias[o]), float4.
// ---------------------------------------------------------------------------
__global__ __launch_bounds__(256) void k_act(const float* __restrict__ P,
                                             const float* __restrict__ b,
                                             float* __restrict__ T) {
    const int e = (blockIdx.x * 256 + threadIdx.x) * 4;
    const int o = e & (F_ - 1);
    float4 a = *(const float4*)(b + o);
#pragma unroll
    for (int ps = 0; ps < GEMM_KS; ++ps) {
        float4 v = *(const float4*)(P + (size_t)ps * NE + e);
        a.x += v.x; a.y += v.y; a.z += v.z; a.w += v.w;
    }
    a.x = fmaxf(a.x, 0.f); a.y = fmaxf(a.y, 0.f);
    a.z = fmaxf(a.z, 0.f); a.w = fmaxf(a.w, 0.f);
    *(float4*)(T + e) = a;
}

// ---------------------------------------------------------------------------
// Kernel 5: reduce partials + bias -> relu -> BatchNorm -> (+ GIN-2 agg) -> H
// Block owns [64 c][16 o]; grid 128. sum_c(BN(x)) == 64*beta exactly.
// ---------------------------------------------------------------------------
__global__ __launch_bounds__(256) void k_bnh(const float* __restrict__ P,
                                             const float* __restrict__ bias,
                                             const float* __restrict__ g,
                                             const float* __restrict__ beta,
                                             float* __restrict__ H) {
    __shared__ float xs[64 * 20];
    __shared__ float gs[64];
    __shared__ float gs2[64];
    __shared__ float mL[16];
    __shared__ float rL[16];
    const int t  = threadIdx.x;
    const int o0 = blockIdx.x * 16;
    const int c  = t >> 2;
    const int oq = (t & 3) * 4;

    float4 x = *(const float4*)(bias + o0 + oq);
#pragma unroll
    for (int ps = 0; ps < GEMM_KS; ++ps) {
        float4 v = *(const float4*)(P + (size_t)ps * NE + c * F_ + o0 + oq);
        x.x += v.x; x.y += v.y; x.z += v.z; x.w += v.w;
    }
    x.x = fmaxf(x.x, 0.f); x.y = fmaxf(x.y, 0.f);
    x.z = fmaxf(x.z, 0.f); x.w = fmaxf(x.w, 0.f);
    xs[c * 20 + oq + 0] = x.x;
    xs[c * 20 + oq + 1] = x.y;
    xs[c * 20 + oq + 2] = x.z;
    xs[c * 20 + oq + 3] = x.w;
    __syncthreads();

    if (t < 64) {
        const int o = t & 15, cg = t >> 4;
        float s = 0.f, s2 = 0.f;
#pragma unroll
        for (int i = 0; i < 16; ++i) {
            float v = xs[(cg * 16 + i) * 20 + o];
            s += v; s2 += v * v;
        }
        gs[cg * 16 + o] = s;
        gs2[cg * 16 + o] = s2;
    }
    __syncthreads();
    if (t < 16) {
        float s  = gs[t] + gs[16 + t] + gs[32 + t] + gs[48 + t];
        float s2 = gs2[t] + gs2[16 + t] + gs2[32 + t] + gs2[48 + t];
        float m   = s * (1.f / C_);
        float var = s2 * (1.f / C_) - m * m;
        mL[t] = m;
        rL[t] = 1.f / sqrtf(var + 1e-5f);
    }
    __syncthreads();

    float4 g4 = *(const float4*)(g + o0 + oq);
    float4 b4 = *(const float4*)(beta + o0 + oq);
    float4 r;
    r.x = (x.x - mL[oq + 0]) * rL[oq + 0] * g4.x + b4.x;
    r.y = (x.y - mL[oq + 1]) * rL[oq + 1] * g4.y + b4.y;
    r.z = (x.z - mL[oq + 2]) * rL[oq + 2] * g4.z + b4.z;
    r.w = (x.w - mL[oq + 3]) * rL[oq + 3] * g4.w + b4.w;
    if (c > 0) {   // GIN-2 aggregate: sum_c xn = 64*beta exactly
        r.x += C_ * b4.x; r.y += C_ * b4.y;
        r.z += C_ * b4.z; r.w += C_ * b4.w;
    }
    *(float4*)(H + c * F_ + o0 + oq) = r;
}

// ---------------------------------------------------------------------------
// Kernel 6: reduce partials + bias -> relu -> BatchNorm -> out (no agg).
// ---------------------------------------------------------------------------
__global__ __launch_bounds__(256) void k_bn_out(const float* __restrict__ P,
                                                const float* __restrict__ bias,
                                                const float* __restrict__ g,
                                                const float* __restrict__ beta,
                                                float* __restrict__ out) {
    __shared__ float xs[64 * 20];
    __shared__ float gs[64];
    __shared__ float gs2[64];
    __shared__ float mL[16];
    __shared__ float rL[16];
    const int t  = threadIdx.x;
    const int o0 = blockIdx.x * 16;
    const int c  = t >> 2;
    const int oq = (t & 3) * 4;

    float4 x = *(const float4*)(bias + o0 + oq);
#pragma unroll
    for (int ps = 0; ps < GEMM_KS; ++ps) {
        float4 v = *(const float4*)(P + (size_t)ps * NE + c * F_ + o0 + oq);
        x.x += v.x; x.y += v.y; x.z += v.z; x.w += v.w;
    }
    x.x = fmaxf(x.x, 0.f); x.y = fmaxf(x.y, 0.f);
    x.z = fmaxf(x.z, 0.f); x.w = fmaxf(x.w, 0.f);
    xs[c * 20 + oq + 0] = x.x;
    xs[c * 20 + oq + 1] = x.y;
    xs[c * 20 + oq + 2] = x.z;
    xs[c * 20 + oq + 3] = x.w;
    __syncthreads();

    if (t < 64) {
        const int o = t & 15, cg = t >> 4;
        float s = 0.f, s2 = 0.f;
#pragma unroll
        for (int i = 0; i < 16; ++i) {
            float v = xs[(cg * 16 + i) * 20 + o];
            s += v; s2 += v * v;
        }
        gs[cg * 16 + o] = s;
        gs2[cg * 16 + o] = s2;
    }
    __syncthreads();
    if (t < 16) {
        float s  = gs[t] + gs[16 + t] + gs[32 + t] + gs[48 + t];
        float s2 = gs2[t] + gs2[16 + t] + gs2[32 + t] + gs2[48 + t];
        float m   = s * (1.f / C_);
        float var = s2 * (1.f / C_) - m * m;
        mL[t] = m;
        rL[t] = 1.f / sqrtf(var + 1e-5f);
    }
    __syncthreads();

    float4 g4 = *(const float4*)(g + o0 + oq);
    float4 b4 = *(const float4*)(beta + o0 + oq);
    float4 r;
    r.x = (x.x - mL[oq + 0]) * rL[oq + 0] * g4.x + b4.x;
    r.y = (x.y - mL[oq + 1]) * rL[oq + 1] * g4.y + b4.y;
    r.z = (x.z - mL[oq + 2]) * rL[oq + 2] * g4.z + b4.z;
    r.w = (x.w - mL[oq + 3]) * rL[oq + 3] * g4.w + b4.w;
    *(float4*)(out + c * F_ + o0 + oq) = r;
}

extern "C" void kernel_launch(void* const* d_in, const int* in_sizes, int n_in,
                              void* d_out, int out_size, void* d_ws, size_t ws_size,
                              hipStream_t stream) {
    const float* p   = (const float*)d_in[0];
    const float* cW  = (const float*)d_in[1];
    const float* cb  = (const float*)d_in[2];
    const float* W1a = (const float*)d_in[3];
    const float* b1a = (const float*)d_in[4];
    const float* W1b = (const float*)d_in[5];
    const float* b1b = (const float*)d_in[6];
    const float* g1  = (const float*)d_in[7];
    const float* be1 = (const float*)d_in[8];
    const float* W2a = (const float*)d_in[9];
    const float* b2a = (const float*)d_in[10];
    const float* W2b = (const float*)d_in[11];
    const float* b2b = (const float*)d_in[12];
    const float* g2  = (const float*)d_in[13];
    const float* be2 = (const float*)d_in[14];
    float* out = (float*)d_out;
    float* ws  = (float*)d_ws;

    float* P0 = ws;                         // [8][64][2048]
    float* PA = P0 + (size_t)GEMV_KS * NE;  // [16][64][2048]
    float* PB = PA + (size_t)GEMM_KS * NE;  // [16][64][2048]
    float* H1 = PB + (size_t)GEMM_KS * NE;
    float* T1 = H1 + NE;
    float* H2 = T1 + NE;
    float* T2 = H2 + NE;

    // child MLP partials (the 1.07 GB streaming read)
    k_gemv<<<dim3(64, 2, GEMV_KS), 256, 0, stream>>>(p, cW, P0);
    // reduce + relu + GIN-1 aggregate
    k_h1<<<128, 256, 0, stream>>>(P0, cb, H1);
    // GIN 1
    k_gemm<<<dim3(32, GEMM_KS), 256, 0, stream>>>(H1, W1a, PA);
    k_act<<<128, 256, 0, stream>>>(PA, b1a, T1);
    k_gemm<<<dim3(32, GEMM_KS), 256, 0, stream>>>(T1, W1b, PB);
    // relu + BN1 + GIN-2 aggregate
    k_bnh<<<128, 256, 0, stream>>>(PB, b1b, g1, be1, H2);
    // GIN 2
    k_gemm<<<dim3(32, GEMM_KS), 256, 0, stream>>>(H2, W2a, PA);
    k_act<<<128, 256, 0, stream>>>(PA, b2a, T2);
    k_gemm<<<dim3(32, GEMM_KS), 256, 0, stream>>>(T2, W2b, PB);
    // relu + BN2 -> output
    k_bn_out<<<128, 256, 0, stream>>>(PB, b2b, g2, be2, out);
}

// Round 7
// 310.923 us; speedup vs baseline: 1.7658x; 1.0594x over previous
//
#include <hip/hip_runtime.h>
#include <hip/hip_bf16.h>

#define F_ 2048
#define C_ 64
#define NE (C_ * F_)   // 131072 elements per [64,2048] activation
#define PGV 16         // gemv partials (f-chunk = 128)
#define PGM 32         // gemm partials (k-chunk = 64)

// ---------------------------------------------------------------------------
// Kernel 1: P[fc][c][o] = sum_{f in chunk fc} p[f] * W[c,f,o]   (f32)
// grid (64 c, 16 f-chunks) = 1024 blocks; each block streams a CONTIGUOUS
// 1 MB of W (128 rows x 8 KB). Thread t owns cols t*4 and 1024+t*4.
// ---------------------------------------------------------------------------
__global__ __launch_bounds__(256) void k_gemv(const float* __restrict__ p,
                                              const float* __restrict__ W,
                                              float* __restrict__ P0) {
    __shared__ float lp[128];
    const int c  = blockIdx.x;
    const int fc = blockIdx.y;
    const int t  = threadIdx.x;
    const int f0 = fc * 128;
    if (t < 128) lp[t] = p[f0 + t];
    __syncthreads();

    const float* Wp = W + ((size_t)c << 22) + (size_t)f0 * F_;
    float4 aL = make_float4(0.f, 0.f, 0.f, 0.f);
    float4 aH = make_float4(0.f, 0.f, 0.f, 0.f);
#pragma unroll 4
    for (int ff = 0; ff < 128; ++ff) {
        float pv = lp[ff];
        float4 wl = *(const float4*)(Wp + (size_t)ff * F_ + t * 4);
        float4 wh = *(const float4*)(Wp + (size_t)ff * F_ + 1024 + t * 4);
        aL.x += pv * wl.x; aL.y += pv * wl.y; aL.z += pv * wl.z; aL.w += pv * wl.w;
        aH.x += pv * wh.x; aH.y += pv * wh.y; aH.z += pv * wh.z; aH.w += pv * wh.w;
    }
    float* dst = P0 + (size_t)fc * NE + c * F_;
    *(float4*)(dst + t * 4) = aL;
    *(float4*)(dst + 1024 + t * 4) = aH;
}

// ---------------------------------------------------------------------------
// Kernel 2: reduce 16 gemv partials + child_b -> relu -> GIN-1 agg -> H1 (f32)
// Block owns [64 c][16 o]; grid 128.
// ---------------------------------------------------------------------------
__global__ __launch_bounds__(256) void k_h1(const float* __restrict__ P0,
                                            const float* __restrict__ cb,
                                            float* __restrict__ H1) {
    __shared__ float xs[64 * 20];
    __shared__ float gs[64];
    __shared__ float aggL[16];
    const int t  = threadIdx.x;
    const int o0 = blockIdx.x * 16;
    const int c  = t >> 2;
    const int oq = (t & 3) * 4;

    float4 x = *(const float4*)(cb + c * F_ + o0 + oq);
#pragma unroll
    for (int ps = 0; ps < PGV; ++ps) {
        float4 v = *(const float4*)(P0 + (size_t)ps * NE + c * F_ + o0 + oq);
        x.x += v.x; x.y += v.y; x.z += v.z; x.w += v.w;
    }
    x.x = fmaxf(x.x, 0.f); x.y = fmaxf(x.y, 0.f);
    x.z = fmaxf(x.z, 0.f); x.w = fmaxf(x.w, 0.f);
    xs[c * 20 + oq + 0] = x.x;
    xs[c * 20 + oq + 1] = x.y;
    xs[c * 20 + oq + 2] = x.z;
    xs[c * 20 + oq + 3] = x.w;
    __syncthreads();

    if (t < 64) {
        const int o = t & 15, cg = t >> 4;
        float s = 0.f;
#pragma unroll
        for (int i = 0; i < 16; ++i) s += xs[(cg * 16 + i) * 20 + o];
        gs[cg * 16 + o] = s;
    }
    __syncthreads();
    if (t < 16) aggL[t] = gs[t] + gs[16 + t] + gs[32 + t] + gs[48 + t];
    __syncthreads();

    float4 r = x;
    if (c > 0) {
        r.x += aggL[oq + 0]; r.y += aggL[oq + 1];
        r.z += aggL[oq + 2]; r.w += aggL[oq + 3];
    }
    *(float4*)(H1 + c * F_ + o0 + oq) = r;
}

// ---------------------------------------------------------------------------
// Kernel 3: f32 GEMM partials  P[ks][c][n] = sum_{k in chunk} Hm[c,k]*W[k,n]
// grid (32 n-tiles of 64, 32 k-chunks of 64) = 1024 blocks (4/CU, 16 w/CU).
// H chunk [64][64] in LDS stride 68 (broadcast float4 reads, conflict-free).
// Wave: 16 rows; lane: 1 col. 1024 FMA/thread, 16-deep ILP.
// ---------------------------------------------------------------------------
__global__ __launch_bounds__(256) void k_gemm(const float* __restrict__ Hm,
                                              const float* __restrict__ W,
                                              float* __restrict__ P) {
    __shared__ float lh[64 * 68];   // 17.4 KB
    const int n0 = blockIdx.x * 64;
    const int k0 = blockIdx.y * 64;
    const int t  = threadIdx.x;

#pragma unroll
    for (int it = 0; it < 4; ++it) {
        int s  = t + it * 256;          // 0..1023 float4 slots
        int c  = s >> 4;                // 16 slots per row
        int k4 = (s & 15) * 4;
        *(float4*)&lh[c * 68 + k4] = *(const float4*)&Hm[c * F_ + k0 + k4];
    }
    __syncthreads();

    const int w   = t >> 6;
    const int l   = t & 63;
    const int rb  = w * 16;
    const int col = n0 + l;

    float acc[16];
#pragma unroll
    for (int i = 0; i < 16; ++i) acc[i] = 0.f;

#pragma unroll 4
    for (int kq = 0; kq < 16; ++kq) {
        const float w0 = W[(size_t)(k0 + kq * 4 + 0) * F_ + col];
        const float w1 = W[(size_t)(k0 + kq * 4 + 1) * F_ + col];
        const float w2 = W[(size_t)(k0 + kq * 4 + 2) * F_ + col];
        const float w3 = W[(size_t)(k0 + kq * 4 + 3) * F_ + col];
#pragma unroll
        for (int r = 0; r < 16; ++r) {
            float4 h = *(const float4*)&lh[(rb + r) * 68 + kq * 4];
            acc[r] += h.x * w0 + h.y * w1 + h.z * w2 + h.w * w3;
        }
    }

    float* dst = P + (size_t)blockIdx.y * NE + rb * F_ + col;
#pragma unroll
    for (int r = 0; r < 16; ++r)
        dst[r * F_] = acc[r];
}

// ---------------------------------------------------------------------------
// Kernel 4: T = relu(sum_p P[p] + bias[o])  (f32), float4.
// ---------------------------------------------------------------------------
__global__ __launch_bounds__(256) void k_act(const float* __restrict__ P,
                                             const float* __restrict__ b,
                                             float* __restrict__ T) {
    const int e = (blockIdx.x * 256 + threadIdx.x) * 4;
    const int o = e & (F_ - 1);
    float4 a = *(const float4*)(b + o);
#pragma unroll 8
    for (int ps = 0; ps < PGM; ++ps) {
        float4 v = *(const float4*)(P + (size_t)ps * NE + e);
        a.x += v.x; a.y += v.y; a.z += v.z; a.w += v.w;
    }
    a.x = fmaxf(a.x, 0.f); a.y = fmaxf(a.y, 0.f);
    a.z = fmaxf(a.z, 0.f); a.w = fmaxf(a.w, 0.f);
    *(float4*)(T + e) = a;
}

// ---------------------------------------------------------------------------
// Kernel 5: reduce partials + bias -> relu -> BatchNorm -> (+ GIN-2 agg) -> H
// Block owns [64 c][16 o]; grid 128. sum_c(BN(x)) == 64*beta exactly.
// ---------------------------------------------------------------------------
__global__ __launch_bounds__(256) void k_bnh(const float* __restrict__ P,
                                             const float* __restrict__ bias,
                                             const float* __restrict__ g,
                                             const float* __restrict__ beta,
                                             float* __restrict__ H) {
    __shared__ float xs[64 * 20];
    __shared__ float gs[64];
    __shared__ float gs2[64];
    __shared__ float mL[16];
    __shared__ float rL[16];
    const int t  = threadIdx.x;
    const int o0 = blockIdx.x * 16;
    const int c  = t >> 2;
    const int oq = (t & 3) * 4;

    float4 x = *(const float4*)(bias + o0 + oq);
#pragma unroll 8
    for (int ps = 0; ps < PGM; ++ps) {
        float4 v = *(const float4*)(P + (size_t)ps * NE + c * F_ + o0 + oq);
        x.x += v.x; x.y += v.y; x.z += v.z; x.w += v.w;
    }
    x.x = fmaxf(x.x, 0.f); x.y = fmaxf(x.y, 0.f);
    x.z = fmaxf(x.z, 0.f); x.w = fmaxf(x.w, 0.f);
    xs[c * 20 + oq + 0] = x.x;
    xs[c * 20 + oq + 1] = x.y;
    xs[c * 20 + oq + 2] = x.z;
    xs[c * 20 + oq + 3] = x.w;
    __syncthreads();

    if (t < 64) {
        const int o = t & 15, cg = t >> 4;
        float s = 0.f, s2 = 0.f;
#pragma unroll
        for (int i = 0; i < 16; ++i) {
            float v = xs[(cg * 16 + i) * 20 + o];
            s += v; s2 += v * v;
        }
        gs[cg * 16 + o] = s;
        gs2[cg * 16 + o] = s2;
    }
    __syncthreads();
    if (t < 16) {
        float s  = gs[t] + gs[16 + t] + gs[32 + t] + gs[48 + t];
        float s2 = gs2[t] + gs2[16 + t] + gs2[32 + t] + gs2[48 + t];
        float m   = s * (1.f / C_);
        float var = s2 * (1.f / C_) - m * m;
        mL[t] = m;
        rL[t] = 1.f / sqrtf(var + 1e-5f);
    }
    __syncthreads();

    float4 g4 = *(const float4*)(g + o0 + oq);
    float4 b4 = *(const float4*)(beta + o0 + oq);
    float4 r;
    r.x = (x.x - mL[oq + 0]) * rL[oq + 0] * g4.x + b4.x;
    r.y = (x.y - mL[oq + 1]) * rL[oq + 1] * g4.y + b4.y;
    r.z = (x.z - mL[oq + 2]) * rL[oq + 2] * g4.z + b4.z;
    r.w = (x.w - mL[oq + 3]) * rL[oq + 3] * g4.w + b4.w;
    if (c > 0) {   // GIN-2 aggregate: sum_c xn = 64*beta exactly
        r.x += C_ * b4.x; r.y += C_ * b4.y;
        r.z += C_ * b4.z; r.w += C_ * b4.w;
    }
    *(float4*)(H + c * F_ + o0 + oq) = r;
}

// ---------------------------------------------------------------------------
// Kernel 6: reduce partials + bias -> relu -> BatchNorm -> out (f32, no agg).
// ---------------------------------------------------------------------------
__global__ __launch_bounds__(256) void k_bn_out(const float* __restrict__ P,
                                                const float* __restrict__ bias,
                                                const float* __restrict__ g,
                                                const float* __restrict__ beta,
                                                float* __restrict__ out) {
    __shared__ float xs[64 * 20];
    __shared__ float gs[64];
    __shared__ float gs2[64];
    __shared__ float mL[16];
    __shared__ float rL[16];
    const int t  = threadIdx.x;
    const int o0 = blockIdx.x * 16;
    const int c  = t >> 2;
    const int oq = (t & 3) * 4;

    float4 x = *(const float4*)(bias + o0 + oq);
#pragma unroll 8
    for (int ps = 0; ps < PGM; ++ps) {
        float4 v = *(const float4*)(P + (size_t)ps * NE + c * F_ + o0 + oq);
        x.x += v.x; x.y += v.y; x.z += v.z; x.w += v.w;
    }
    x.x = fmaxf(x.x, 0.f); x.y = fmaxf(x.y, 0.f);
    x.z = fmaxf(x.z, 0.f); x.w = fmaxf(x.w, 0.f);
    xs[c * 20 + oq + 0] = x.x;
    xs[c * 20 + oq + 1] = x.y;
    xs[c * 20 + oq + 2] = x.z;
    xs[c * 20 + oq + 3] = x.w;
    __syncthreads();

    if (t < 64) {
        const int o = t & 15, cg = t >> 4;
        float s = 0.f, s2 = 0.f;
#pragma unroll
        for (int i = 0; i < 16; ++i) {
            float v = xs[(cg * 16 + i) * 20 + o];
            s += v; s2 += v * v;
        }
        gs[cg * 16 + o] = s;
        gs2[cg * 16 + o] = s2;
    }
    __syncthreads();
    if (t < 16) {
        float s  = gs[t] + gs[16 + t] + gs[32 + t] + gs[48 + t];
        float s2 = gs2[t] + gs2[16 + t] + gs2[32 + t] + gs2[48 + t];
        float m   = s * (1.f / C_);
        float var = s2 * (1.f / C_) - m * m;
        mL[t] = m;
        rL[t] = 1.f / sqrtf(var + 1e-5f);
    }
    __syncthreads();

    float4 g4 = *(const float4*)(g + o0 + oq);
    float4 b4 = *(const float4*)(beta + o0 + oq);
    float4 r;
    r.x = (x.x - mL[oq + 0]) * rL[oq + 0] * g4.x + b4.x;
    r.y = (x.y - mL[oq + 1]) * rL[oq + 1] * g4.y + b4.y;
    r.z = (x.z - mL[oq + 2]) * rL[oq + 2] * g4.z + b4.z;
    r.w = (x.w - mL[oq + 3]) * rL[oq + 3] * g4.w + b4.w;
    *(float4*)(out + c * F_ + o0 + oq) = r;
}

extern "C" void kernel_launch(void* const* d_in, const int* in_sizes, int n_in,
                              void* d_out, int out_size, void* d_ws, size_t ws_size,
                              hipStream_t stream) {
    const float* p   = (const float*)d_in[0];
    const float* cW  = (const float*)d_in[1];
    const float* cb  = (const float*)d_in[2];
    const float* W1a = (const float*)d_in[3];
    const float* b1a = (const float*)d_in[4];
    const float* W1b = (const float*)d_in[5];
    const float* b1b = (const float*)d_in[6];
    const float* g1  = (const float*)d_in[7];
    const float* be1 = (const float*)d_in[8];
    const float* W2a = (const float*)d_in[9];
    const float* b2a = (const float*)d_in[10];
    const float* W2b = (const float*)d_in[11];
    const float* b2b = (const float*)d_in[12];
    const float* g2  = (const float*)d_in[13];
    const float* be2 = (const float*)d_in[14];
    float* out = (float*)d_out;
    float* ws  = (float*)d_ws;

    // Single partial buffer P [32][64][2048] f32 (16.8 MB), reused by the
    // gemv (first 16 slots) and all 4 GEMMs — every reuse is serialized by
    // stream order. Activations follow (4 x 0.5 MB). Total ws = 18.9 MB.
    float* P  = ws;
    float* H1 = ws + (size_t)PGM * NE;
    float* T1 = H1 + NE;
    float* H2 = T1 + NE;
    float* T2 = H2 + NE;

    // child MLP partials (the 1.07 GB streaming read, contiguous per block)
    k_gemv<<<dim3(64, PGV), 256, 0, stream>>>(p, cW, P);
    // reduce + relu + GIN-1 aggregate
    k_h1<<<128, 256, 0, stream>>>(P, cb, H1);
    // GIN 1
    k_gemm<<<dim3(32, PGM), 256, 0, stream>>>(H1, W1a, P);
    k_act<<<128, 256, 0, stream>>>(P, b1a, T1);
    k_gemm<<<dim3(32, PGM), 256, 0, stream>>>(T1, W1b, P);
    // relu + BN1 + GIN-2 aggregate
    k_bnh<<<128, 256, 0, stream>>>(P, b1b, g1, be1, H2);
    // GIN 2
    k_gemm<<<dim3(32, PGM), 256, 0, stream>>>(H2, W2a, P);
    k_act<<<128, 256, 0, stream>>>(P, b2a, T2);
    k_gemm<<<dim3(32, PGM), 256, 0, stream>>>(T2, W2b, P);
    // relu + BN2 -> output
    k_bn_out<<<128, 256, 0, stream>>>(P, b2b, g2, be2, out);
}

// Round 8
// 254.951 us; speedup vs baseline: 2.1535x; 1.2195x over previous
//
#include <hip/hip_runtime.h>
#include <hip/hip_bf16.h>

#define F_ 2048
#define C_ 64
#define NE (C_ * F_)   // 131072 elements per [64,2048] activation
#define PGV 16         // gemv partials (f-chunk = 128)
#define PGM 32         // gemm partials (k-chunk = 64)

typedef __attribute__((ext_vector_type(4))) float f32x4;

// ---------------------------------------------------------------------------
// Kernel 1: P[fc][c][o] = sum_{f in chunk fc} p[f] * W[c,f,o]   (f32)
// grid (64 c, 16 f-chunks) = 1024 blocks; each block streams a CONTIGUOUS
// 1 MB of W via nontemporal loads (read-once data, don't pollute L2).
// ---------------------------------------------------------------------------
__global__ __launch_bounds__(256) void k_gemv(const float* __restrict__ p,
                                              const float* __restrict__ W,
                                              float* __restrict__ P0) {
    __shared__ float lp[128];
    const int c  = blockIdx.x;
    const int fc = blockIdx.y;
    const int t  = threadIdx.x;
    const int f0 = fc * 128;
    if (t < 128) lp[t] = p[f0 + t];
    __syncthreads();

    const float* Wp = W + ((size_t)c << 22) + (size_t)f0 * F_;
    f32x4 aL = (f32x4)(0.f);
    f32x4 aH = (f32x4)(0.f);
#pragma unroll 4
    for (int ff = 0; ff < 128; ++ff) {
        float pv = lp[ff];
        f32x4 wl = __builtin_nontemporal_load((const f32x4*)(Wp + (size_t)ff * F_ + t * 4));
        f32x4 wh = __builtin_nontemporal_load((const f32x4*)(Wp + (size_t)ff * F_ + 1024 + t * 4));
        aL += pv * wl;
        aH += pv * wh;
    }
    float* dst = P0 + (size_t)fc * NE + c * F_;
    *(f32x4*)(dst + t * 4) = aL;
    *(f32x4*)(dst + 1024 + t * 4) = aH;
}

// ---------------------------------------------------------------------------
// Kernel 2: reduce 16 gemv partials + child_b -> relu -> GIN-1 agg -> H1 (f32)
// Block owns [64 c][16 o]; grid 128.
// ---------------------------------------------------------------------------
__global__ __launch_bounds__(256) void k_h1(const float* __restrict__ P0,
                                            const float* __restrict__ cb,
                                            float* __restrict__ H1) {
    __shared__ float xs[64 * 20];
    __shared__ float gs[64];
    __shared__ float aggL[16];
    const int t  = threadIdx.x;
    const int o0 = blockIdx.x * 16;
    const int c  = t >> 2;
    const int oq = (t & 3) * 4;

    float4 x = *(const float4*)(cb + c * F_ + o0 + oq);
#pragma unroll
    for (int ps = 0; ps < PGV; ++ps) {
        float4 v = *(const float4*)(P0 + (size_t)ps * NE + c * F_ + o0 + oq);
        x.x += v.x; x.y += v.y; x.z += v.z; x.w += v.w;
    }
    x.x = fmaxf(x.x, 0.f); x.y = fmaxf(x.y, 0.f);
    x.z = fmaxf(x.z, 0.f); x.w = fmaxf(x.w, 0.f);
    xs[c * 20 + oq + 0] = x.x;
    xs[c * 20 + oq + 1] = x.y;
    xs[c * 20 + oq + 2] = x.z;
    xs[c * 20 + oq + 3] = x.w;
    __syncthreads();

    if (t < 64) {
        const int o = t & 15, cg = t >> 4;
        float s = 0.f;
#pragma unroll
        for (int i = 0; i < 16; ++i) s += xs[(cg * 16 + i) * 20 + o];
        gs[cg * 16 + o] = s;
    }
    __syncthreads();
    if (t < 16) aggL[t] = gs[t] + gs[16 + t] + gs[32 + t] + gs[48 + t];
    __syncthreads();

    float4 r = x;
    if (c > 0) {
        r.x += aggL[oq + 0]; r.y += aggL[oq + 1];
        r.z += aggL[oq + 2]; r.w += aggL[oq + 3];
    }
    *(float4*)(H1 + c * F_ + o0 + oq) = r;
}

// ---------------------------------------------------------------------------
// Kernel 3: f32 GEMM partials, 4x4 micro-tile.
// P[ks][c][n] = sum_{k in chunk ks} Hm[c,k] * W[k,n]
// grid (32 n-tiles of 64, 32 k-chunks of 64) = 1024 blocks (4/CU, 16 w/CU).
// LDS: Ht [k][m] (transposed) + Ws [k][n], both stride 68 (34.8 KB total).
// Thread (tm4, tn4): per k, 2 vector b128 reads -> 16 FMA (VALU-bound).
// ---------------------------------------------------------------------------
__global__ __launch_bounds__(256) void k_gemm(const float* __restrict__ Hm,
                                              const float* __restrict__ W,
                                              float* __restrict__ P) {
    __shared__ float Ht[64 * 68];   // [k][m]
    __shared__ float Ws[64 * 68];   // [k][n]
    const int n0 = blockIdx.x * 64;
    const int k0 = blockIdx.y * 64;
    const int t  = threadIdx.x;

#pragma unroll
    for (int it = 0; it < 4; ++it) {
        int s = t + it * 256;            // 0..1023
        {   // H: read [m][k] float4, write transposed scalars
            int m  = s >> 4;
            int k4 = (s & 15) * 4;
            float4 h = *(const float4*)&Hm[m * F_ + k0 + k4];
            Ht[(k4 + 0) * 68 + m] = h.x;
            Ht[(k4 + 1) * 68 + m] = h.y;
            Ht[(k4 + 2) * 68 + m] = h.z;
            Ht[(k4 + 3) * 68 + m] = h.w;
        }
        {   // W: read [k][n] float4, write as-is
            int k  = s >> 4;
            int n4 = (s & 15) * 4;
            *(f32x4*)&Ws[k * 68 + n4] =
                *(const f32x4*)&W[(size_t)(k0 + k) * F_ + n0 + n4];
        }
    }
    __syncthreads();

    const int tm4 = (t >> 4) * 4;   // 16 m-groups of 4 rows
    const int tn4 = (t & 15) * 4;   // 16 n-groups of 4 cols

    f32x4 acc0 = (f32x4)(0.f), acc1 = (f32x4)(0.f);
    f32x4 acc2 = (f32x4)(0.f), acc3 = (f32x4)(0.f);

#pragma unroll 4
    for (int k = 0; k < 64; ++k) {
        f32x4 a = *(const f32x4*)&Ht[k * 68 + tm4];
        f32x4 b = *(const f32x4*)&Ws[k * 68 + tn4];
        acc0 += a.x * b;
        acc1 += a.y * b;
        acc2 += a.z * b;
        acc3 += a.w * b;
    }

    float* dst = P + (size_t)blockIdx.y * NE + n0 + tn4;
    *(f32x4*)&dst[(tm4 + 0) * F_] = acc0;
    *(f32x4*)&dst[(tm4 + 1) * F_] = acc1;
    *(f32x4*)&dst[(tm4 + 2) * F_] = acc2;
    *(f32x4*)&dst[(tm4 + 3) * F_] = acc3;
}

// ---------------------------------------------------------------------------
// Kernel 4: T = relu(sum_p P[p] + bias[o])  (f32), float4.
// ---------------------------------------------------------------------------
__global__ __launch_bounds__(256) void k_act(const float* __restrict__ P,
                                             const float* __restrict__ b,
                                             float* __restrict__ T) {
    const int e = (blockIdx.x * 256 + threadIdx.x) * 4;
    const int o = e & (F_ - 1);
    float4 a = *(const float4*)(b + o);
#pragma unroll 8
    for (int ps = 0; ps < PGM; ++ps) {
        float4 v = *(const float4*)(P + (size_t)ps * NE + e);
        a.x += v.x; a.y += v.y; a.z += v.z; a.w += v.w;
    }
    a.x = fmaxf(a.x, 0.f); a.y = fmaxf(a.y, 0.f);
    a.z = fmaxf(a.z, 0.f); a.w = fmaxf(a.w, 0.f);
    *(float4*)(T + e) = a;
}

// ---------------------------------------------------------------------------
// Kernel 5: reduce partials + bias -> relu -> BatchNorm -> (+ GIN-2 agg) -> H
// Block owns [64 c][16 o]; grid 128. sum_c(BN(x)) == 64*beta exactly.
// ---------------------------------------------------------------------------
__global__ __launch_bounds__(256) void k_bnh(const float* __restrict__ P,
                                             const float* __restrict__ bias,
                                             const float* __restrict__ g,
                                             const float* __restrict__ beta,
                                             float* __restrict__ H) {
    __shared__ float xs[64 * 20];
    __shared__ float gs[64];
    __shared__ float gs2[64];
    __shared__ float mL[16];
    __shared__ float rL[16];
    const int t  = threadIdx.x;
    const int o0 = blockIdx.x * 16;
    const int c  = t >> 2;
    const int oq = (t & 3) * 4;

    float4 x = *(const float4*)(bias + o0 + oq);
#pragma unroll 8
    for (int ps = 0; ps < PGM; ++ps) {
        float4 v = *(const float4*)(P + (size_t)ps * NE + c * F_ + o0 + oq);
        x.x += v.x; x.y += v.y; x.z += v.z; x.w += v.w;
    }
    x.x = fmaxf(x.x, 0.f); x.y = fmaxf(x.y, 0.f);
    x.z = fmaxf(x.z, 0.f); x.w = fmaxf(x.w, 0.f);
    xs[c * 20 + oq + 0] = x.x;
    xs[c * 20 + oq + 1] = x.y;
    xs[c * 20 + oq + 2] = x.z;
    xs[c * 20 + oq + 3] = x.w;
    __syncthreads();

    if (t < 64) {
        const int o = t & 15, cg = t >> 4;
        float s = 0.f, s2 = 0.f;
#pragma unroll
        for (int i = 0; i < 16; ++i) {
            float v = xs[(cg * 16 + i) * 20 + o];
            s += v; s2 += v * v;
        }
        gs[cg * 16 + o] = s;
        gs2[cg * 16 + o] = s2;
    }
    __syncthreads();
    if (t < 16) {
        float s  = gs[t] + gs[16 + t] + gs[32 + t] + gs[48 + t];
        float s2 = gs2[t] + gs2[16 + t] + gs2[32 + t] + gs2[48 + t];
        float m   = s * (1.f / C_);
        float var = s2 * (1.f / C_) - m * m;
        mL[t] = m;
        rL[t] = 1.f / sqrtf(var + 1e-5f);
    }
    __syncthreads();

    float4 g4 = *(const float4*)(g + o0 + oq);
    float4 b4 = *(const float4*)(beta + o0 + oq);
    float4 r;
    r.x = (x.x - mL[oq + 0]) * rL[oq + 0] * g4.x + b4.x;
    r.y = (x.y - mL[oq + 1]) * rL[oq + 1] * g4.y + b4.y;
    r.z = (x.z - mL[oq + 2]) * rL[oq + 2] * g4.z + b4.z;
    r.w = (x.w - mL[oq + 3]) * rL[oq + 3] * g4.w + b4.w;
    if (c > 0) {   // GIN-2 aggregate: sum_c xn = 64*beta exactly
        r.x += C_ * b4.x; r.y += C_ * b4.y;
        r.z += C_ * b4.z; r.w += C_ * b4.w;
    }
    *(float4*)(H + c * F_ + o0 + oq) = r;
}

// ---------------------------------------------------------------------------
// Kernel 6: reduce partials + bias -> relu -> BatchNorm -> out (f32, no agg).
// ---------------------------------------------------------------------------
__global__ __launch_bounds__(256) void k_bn_out(const float* __restrict__ P,
                                                const float* __restrict__ bias,
                                                const float* __restrict__ g,
                                                const float* __restrict__ beta,
                                                float* __restrict__ out) {
    __shared__ float xs[64 * 20];
    __shared__ float gs[64];
    __shared__ float gs2[64];
    __shared__ float mL[16];
    __shared__ float rL[16];
    const int t  = threadIdx.x;
    const int o0 = blockIdx.x * 16;
    const int c  = t >> 2;
    const int oq = (t & 3) * 4;

    float4 x = *(const float4*)(bias + o0 + oq);
#pragma unroll 8
    for (int ps = 0; ps < PGM; ++ps) {
        float4 v = *(const float4*)(P + (size_t)ps * NE + c * F_ + o0 + oq);
        x.x += v.x; x.y += v.y; x.z += v.z; x.w += v.w;
    }
    x.x = fmaxf(x.x, 0.f); x.y = fmaxf(x.y, 0.f);
    x.z = fmaxf(x.z, 0.f); x.w = fmaxf(x.w, 0.f);
    xs[c * 20 + oq + 0] = x.x;
    xs[c * 20 + oq + 1] = x.y;
    xs[c * 20 + oq + 2] = x.z;
    xs[c * 20 + oq + 3] = x.w;
    __syncthreads();

    if (t < 64) {
        const int o = t & 15, cg = t >> 4;
        float s = 0.f, s2 = 0.f;
#pragma unroll
        for (int i = 0; i < 16; ++i) {
            float v = xs[(cg * 16 + i) * 20 + o];
            s += v; s2 += v * v;
        }
        gs[cg * 16 + o] = s;
        gs2[cg * 16 + o] = s2;
    }
    __syncthreads();
    if (t < 16) {
        float s  = gs[t] + gs[16 + t] + gs[32 + t] + gs[48 + t];
        float s2 = gs2[t] + gs2[16 + t] + gs2[32 + t] + gs2[48 + t];
        float m   = s * (1.f / C_);
        float var = s2 * (1.f / C_) - m * m;
        mL[t] = m;
        rL[t] = 1.f / sqrtf(var + 1e-5f);
    }
    __syncthreads();

    float4 g4 = *(const float4*)(g + o0 + oq);
    float4 b4 = *(const float4*)(beta + o0 + oq);
    float4 r;
    r.x = (x.x - mL[oq + 0]) * rL[oq + 0] * g4.x + b4.x;
    r.y = (x.y - mL[oq + 1]) * rL[oq + 1] * g4.y + b4.y;
    r.z = (x.z - mL[oq + 2]) * rL[oq + 2] * g4.z + b4.z;
    r.w = (x.w - mL[oq + 3]) * rL[oq + 3] * g4.w + b4.w;
    *(float4*)(out + c * F_ + o0 + oq) = r;
}

extern "C" void kernel_launch(void* const* d_in, const int* in_sizes, int n_in,
                              void* d_out, int out_size, void* d_ws, size_t ws_size,
                              hipStream_t stream) {
    const float* p   = (const float*)d_in[0];
    const float* cW  = (const float*)d_in[1];
    const float* cb  = (const float*)d_in[2];
    const float* W1a = (const float*)d_in[3];
    const float* b1a = (const float*)d_in[4];
    const float* W1b = (const float*)d_in[5];
    const float* b1b = (const float*)d_in[6];
    const float* g1  = (const float*)d_in[7];
    const float* be1 = (const float*)d_in[8];
    const float* W2a = (const float*)d_in[9];
    const float* b2a = (const float*)d_in[10];
    const float* W2b = (const float*)d_in[11];
    const float* b2b = (const float*)d_in[12];
    const float* g2  = (const float*)d_in[13];
    const float* be2 = (const float*)d_in[14];
    float* out = (float*)d_out;
    float* ws  = (float*)d_ws;

    // Single partial buffer P [32][64][2048] f32 (16.8 MB), reused by the
    // gemv (first 16 slots) and all 4 GEMMs; activations follow.
    float* P  = ws;
    float* H1 = ws + (size_t)PGM * NE;
    float* T1 = H1 + NE;
    float* H2 = T1 + NE;
    float* T2 = H2 + NE;

    // child MLP partials (the 1.07 GB streaming read, contiguous per block)
    k_gemv<<<dim3(64, PGV), 256, 0, stream>>>(p, cW, P);
    // reduce + relu + GIN-1 aggregate
    k_h1<<<128, 256, 0, stream>>>(P, cb, H1);
    // GIN 1
    k_gemm<<<dim3(32, PGM), 256, 0, stream>>>(H1, W1a, P);
    k_act<<<128, 256, 0, stream>>>(P, b1a, T1);
    k_gemm<<<dim3(32, PGM), 256, 0, stream>>>(T1, W1b, P);
    // relu + BN1 + GIN-2 aggregate
    k_bnh<<<128, 256, 0, stream>>>(P, b1b, g1, be1, H2);
    // GIN 2
    k_gemm<<<dim3(32, PGM), 256, 0, stream>>>(H2, W2a, P);
    k_act<<<128, 256, 0, stream>>>(P, b2a, T2);
    k_gemm<<<dim3(32, PGM), 256, 0, stream>>>(T2, W2b, P);
    // relu + BN2 -> output
    k_bn_out<<<128, 256, 0, stream>>>(P, b2b, g2, be2, out);
}

// Round 9
// 253.590 us; speedup vs baseline: 2.1650x; 1.0054x over previous
//
#include <hip/hip_runtime.h>
#include <hip/hip_bf16.h>

#define F_ 2048
#define C_ 64
#define NE (C_ * F_)   // 131072 elements per [64,2048] activation
#define PGV 16         // gemv partials (f-chunk = 128)
#define PGM 16         // gemm partials (k-chunk = 128, two-stage)

typedef __attribute__((ext_vector_type(4))) float f32x4;

// ---------------------------------------------------------------------------
// Kernel 1: P[fc][c][o] = sum_{f in chunk fc} p[f] * W[c,f,o]   (f32)
// grid (64 c, 16 f-chunks) = 1024 blocks; each block streams a CONTIGUOUS
// 1 MB of W via nontemporal loads (read-once data, don't pollute L2).
// ---------------------------------------------------------------------------
__global__ __launch_bounds__(256) void k_gemv(const float* __restrict__ p,
                                              const float* __restrict__ W,
                                              float* __restrict__ P0) {
    __shared__ float lp[128];
    const int c  = blockIdx.x;
    const int fc = blockIdx.y;
    const int t  = threadIdx.x;
    const int f0 = fc * 128;
    if (t < 128) lp[t] = p[f0 + t];
    __syncthreads();

    const float* Wp = W + ((size_t)c << 22) + (size_t)f0 * F_;
    f32x4 aL = (f32x4)(0.f);
    f32x4 aH = (f32x4)(0.f);
#pragma unroll 4
    for (int ff = 0; ff < 128; ++ff) {
        float pv = lp[ff];
        f32x4 wl = __builtin_nontemporal_load((const f32x4*)(Wp + (size_t)ff * F_ + t * 4));
        f32x4 wh = __builtin_nontemporal_load((const f32x4*)(Wp + (size_t)ff * F_ + 1024 + t * 4));
        aL += pv * wl;
        aH += pv * wh;
    }
    float* dst = P0 + (size_t)fc * NE + c * F_;
    *(f32x4*)(dst + t * 4) = aL;
    *(f32x4*)(dst + 1024 + t * 4) = aH;
}

// ---------------------------------------------------------------------------
// Kernel 2: reduce 16 gemv partials + child_b -> relu -> GIN-1 agg -> H1 (f32)
// Block owns [64 c][8 o]; grid 256 (all CUs active). Thread: c=t>>2, 2 o.
// ---------------------------------------------------------------------------
__global__ __launch_bounds__(256) void k_h1(const float* __restrict__ P0,
                                            const float* __restrict__ cb,
                                            float* __restrict__ H1) {
    __shared__ float xs[64 * 10];
    __shared__ float gs[32];
    __shared__ float aggL[8];
    const int t  = threadIdx.x;
    const int o0 = blockIdx.x * 8;
    const int c  = t >> 2;
    const int j  = (t & 3) * 2;

    float2 x = *(const float2*)(cb + c * F_ + o0 + j);
#pragma unroll
    for (int ps = 0; ps < PGV; ++ps) {
        float2 v = *(const float2*)(P0 + (size_t)ps * NE + c * F_ + o0 + j);
        x.x += v.x; x.y += v.y;
    }
    x.x = fmaxf(x.x, 0.f); x.y = fmaxf(x.y, 0.f);
    xs[c * 10 + j + 0] = x.x;
    xs[c * 10 + j + 1] = x.y;
    __syncthreads();

    if (t < 32) {                    // stage 1: 4 groups of 16 c
        const int o = t & 7, cg = t >> 3;
        float s = 0.f;
#pragma unroll
        for (int i = 0; i < 16; ++i) s += xs[(cg * 16 + i) * 10 + o];
        gs[cg * 8 + o] = s;
    }
    __syncthreads();
    if (t < 8) aggL[t] = gs[t] + gs[8 + t] + gs[16 + t] + gs[24 + t];
    __syncthreads();

    float2 r = x;
    if (c > 0) { r.x += aggL[j]; r.y += aggL[j + 1]; }
    *(float2*)(H1 + c * F_ + o0 + j) = r;
}

// ---------------------------------------------------------------------------
// Kernel 3: f32 GEMM partials, 4x4 micro-tile, TWO-STAGE k-chunk of 128.
// P[ks][c][n] = sum_{k in chunk ks} Hm[c,k] * W[k,n]
// grid (32 n-tiles of 64, 16 k-chunks of 128) = 512 blocks (2/CU, 8 w/CU).
// LDS: Ht [k64][m] (transposed) + Ws [k64][n], stride 68; reused per half.
// W staged nontemporal (read-once stream).
// ---------------------------------------------------------------------------
__global__ __launch_bounds__(256) void k_gemm(const float* __restrict__ Hm,
                                              const float* __restrict__ W,
                                              float* __restrict__ P) {
    __shared__ float Ht[64 * 68];   // [k][m]
    __shared__ float Ws[64 * 68];   // [k][n]
    const int n0 = blockIdx.x * 64;
    const int k0 = blockIdx.y * 128;
    const int t  = threadIdx.x;
    const int tm4 = (t >> 4) * 4;   // 16 m-groups of 4 rows
    const int tn4 = (t & 15) * 4;   // 16 n-groups of 4 cols

    f32x4 acc0 = (f32x4)(0.f), acc1 = (f32x4)(0.f);
    f32x4 acc2 = (f32x4)(0.f), acc3 = (f32x4)(0.f);

    for (int half = 0; half < 2; ++half) {
        const int kh = k0 + half * 64;
        if (half) __syncthreads();   // all waves done with previous LDS tile
#pragma unroll
        for (int it = 0; it < 4; ++it) {
            int s = t + it * 256;            // 0..1023
            {   // H: read [m][k] float4, write transposed scalars
                int m  = s >> 4;
                int k4 = (s & 15) * 4;
                float4 h = *(const float4*)&Hm[m * F_ + kh + k4];
                Ht[(k4 + 0) * 68 + m] = h.x;
                Ht[(k4 + 1) * 68 + m] = h.y;
                Ht[(k4 + 2) * 68 + m] = h.z;
                Ht[(k4 + 3) * 68 + m] = h.w;
            }
            {   // W: read [k][n] float4 (nontemporal), write as-is
                int k  = s >> 4;
                int n4 = (s & 15) * 4;
                f32x4 wv = __builtin_nontemporal_load(
                    (const f32x4*)&W[(size_t)(kh + k) * F_ + n0 + n4]);
                *(f32x4*)&Ws[k * 68 + n4] = wv;
            }
        }
        __syncthreads();

#pragma unroll 4
        for (int k = 0; k < 64; ++k) {
            f32x4 a = *(const f32x4*)&Ht[k * 68 + tm4];
            f32x4 b = *(const f32x4*)&Ws[k * 68 + tn4];
            acc0 += a.x * b;
            acc1 += a.y * b;
            acc2 += a.z * b;
            acc3 += a.w * b;
        }
    }

    float* dst = P + (size_t)blockIdx.y * NE + n0 + tn4;
    *(f32x4*)&dst[(tm4 + 0) * F_] = acc0;
    *(f32x4*)&dst[(tm4 + 1) * F_] = acc1;
    *(f32x4*)&dst[(tm4 + 2) * F_] = acc2;
    *(f32x4*)&dst[(tm4 + 3) * F_] = acc3;
}

// ---------------------------------------------------------------------------
// Kernel 4: T = relu(sum_p P[p] + bias[o])  (f32), float2, grid 256.
// ---------------------------------------------------------------------------
__global__ __launch_bounds__(256) void k_act(const float* __restrict__ P,
                                             const float* __restrict__ b,
                                             float* __restrict__ T) {
    const int e = (blockIdx.x * 256 + threadIdx.x) * 2;
    const int o = e & (F_ - 1);
    float2 a = *(const float2*)(b + o);
#pragma unroll 8
    for (int ps = 0; ps < PGM; ++ps) {
        float2 v = *(const float2*)(P + (size_t)ps * NE + e);
        a.x += v.x; a.y += v.y;
    }
    a.x = fmaxf(a.x, 0.f); a.y = fmaxf(a.y, 0.f);
    *(float2*)(T + e) = a;
}

// ---------------------------------------------------------------------------
// Kernel 5: reduce partials + bias -> relu -> BatchNorm -> (+ GIN-2 agg) -> H
// Block owns [64 c][8 o]; grid 256. sum_c(BN(x)) == 64*beta exactly.
// ---------------------------------------------------------------------------
__global__ __launch_bounds__(256) void k_bnh(const float* __restrict__ P,
                                             const float* __restrict__ bias,
                                             const float* __restrict__ g,
                                             const float* __restrict__ beta,
                                             float* __restrict__ H) {
    __shared__ float xs[64 * 10];
    __shared__ float gs[32];
    __shared__ float gs2[32];
    __shared__ float mL[8];
    __shared__ float rL[8];
    const int t  = threadIdx.x;
    const int o0 = blockIdx.x * 8;
    const int c  = t >> 2;
    const int j  = (t & 3) * 2;

    float2 x = *(const float2*)(bias + o0 + j);
#pragma unroll 8
    for (int ps = 0; ps < PGM; ++ps) {
        float2 v = *(const float2*)(P + (size_t)ps * NE + c * F_ + o0 + j);
        x.x += v.x; x.y += v.y;
    }
    x.x = fmaxf(x.x, 0.f); x.y = fmaxf(x.y, 0.f);
    xs[c * 10 + j + 0] = x.x;
    xs[c * 10 + j + 1] = x.y;
    __syncthreads();

    if (t < 32) {
        const int o = t & 7, cg = t >> 3;
        float s = 0.f, s2 = 0.f;
#pragma unroll
        for (int i = 0; i < 16; ++i) {
            float v = xs[(cg * 16 + i) * 10 + o];
            s += v; s2 += v * v;
        }
        gs[cg * 8 + o] = s;
        gs2[cg * 8 + o] = s2;
    }
    __syncthreads();
    if (t < 8) {
        float s  = gs[t] + gs[8 + t] + gs[16 + t] + gs[24 + t];
        float s2 = gs2[t] + gs2[8 + t] + gs2[16 + t] + gs2[24 + t];
        float m   = s * (1.f / C_);
        float var = s2 * (1.f / C_) - m * m;
        mL[t] = m;
        rL[t] = 1.f / sqrtf(var + 1e-5f);
    }
    __syncthreads();

    float2 g2v = *(const float2*)(g + o0 + j);
    float2 b2v = *(const float2*)(beta + o0 + j);
    float2 r;
    r.x = (x.x - mL[j + 0]) * rL[j + 0] * g2v.x + b2v.x;
    r.y = (x.y - mL[j + 1]) * rL[j + 1] * g2v.y + b2v.y;
    if (c > 0) {   // GIN-2 aggregate: sum_c xn = 64*beta exactly
        r.x += C_ * b2v.x;
        r.y += C_ * b2v.y;
    }
    *(float2*)(H + c * F_ + o0 + j) = r;
}

// ---------------------------------------------------------------------------
// Kernel 6: reduce partials + bias -> relu -> BatchNorm -> out (f32, no agg).
// Block owns [64 c][8 o]; grid 256.
// ---------------------------------------------------------------------------
__global__ __launch_bounds__(256) void k_bn_out(const float* __restrict__ P,
                                                const float* __restrict__ bias,
                                                const float* __restrict__ g,
                                                const float* __restrict__ beta,
                                                float* __restrict__ out) {
    __shared__ float xs[64 * 10];
    __shared__ float gs[32];
    __shared__ float gs2[32];
    __shared__ float mL[8];
    __shared__ float rL[8];
    const int t  = threadIdx.x;
    const int o0 = blockIdx.x * 8;
    const int c  = t >> 2;
    const int j  = (t & 3) * 2;

    float2 x = *(const float2*)(bias + o0 + j);
#pragma unroll 8
    for (int ps = 0; ps < PGM; ++ps) {
        float2 v = *(const float2*)(P + (size_t)ps * NE + c * F_ + o0 + j);
        x.x += v.x; x.y += v.y;
    }
    x.x = fmaxf(x.x, 0.f); x.y = fmaxf(x.y, 0.f);
    xs[c * 10 + j + 0] = x.x;
    xs[c * 10 + j + 1] = x.y;
    __syncthreads();

    if (t < 32) {
        const int o = t & 7, cg = t >> 3;
        float s = 0.f, s2 = 0.f;
#pragma unroll
        for (int i = 0; i < 16; ++i) {
            float v = xs[(cg * 16 + i) * 10 + o];
            s += v; s2 += v * v;
        }
        gs[cg * 8 + o] = s;
        gs2[cg * 8 + o] = s2;
    }
    __syncthreads();
    if (t < 8) {
        float s  = gs[t] + gs[8 + t] + gs[16 + t] + gs[24 + t];
        float s2 = gs2[t] + gs2[8 + t] + gs2[16 + t] + gs2[24 + t];
        float m   = s * (1.f / C_);
        float var = s2 * (1.f / C_) - m * m;
        mL[t] = m;
        rL[t] = 1.f / sqrtf(var + 1e-5f);
    }
    __syncthreads();

    float2 g2v = *(const float2*)(g + o0 + j);
    float2 b2v = *(const float2*)(beta + o0 + j);
    float2 r;
    r.x = (x.x - mL[j + 0]) * rL[j + 0] * g2v.x + b2v.x;
    r.y = (x.y - mL[j + 1]) * rL[j + 1] * g2v.y + b2v.y;
    *(float2*)(out + c * F_ + o0 + j) = r;
}

extern "C" void kernel_launch(void* const* d_in, const int* in_sizes, int n_in,
                              void* d_out, int out_size, void* d_ws, size_t ws_size,
                              hipStream_t stream) {
    const float* p   = (const float*)d_in[0];
    const float* cW  = (const float*)d_in[1];
    const float* cb  = (const float*)d_in[2];
    const float* W1a = (const float*)d_in[3];
    const float* b1a = (const float*)d_in[4];
    const float* W1b = (const float*)d_in[5];
    const float* b1b = (const float*)d_in[6];
    const float* g1  = (const float*)d_in[7];
    const float* be1 = (const float*)d_in[8];
    const float* W2a = (const float*)d_in[9];
    const float* b2a = (const float*)d_in[10];
    const float* W2b = (const float*)d_in[11];
    const float* b2b = (const float*)d_in[12];
    const float* g2  = (const float*)d_in[13];
    const float* be2 = (const float*)d_in[14];
    float* out = (float*)d_out;
    float* ws  = (float*)d_ws;

    // Partial buffer P [16][64][2048] f32 (8.4 MB), shared by gemv (16 slots)
    // and all 4 GEMMs (16 slots); reuse serialized by stream order.
    float* P  = ws;
    float* H1 = ws + (size_t)16 * NE;
    float* T1 = H1 + NE;
    float* H2 = T1 + NE;
    float* T2 = H2 + NE;

    // child MLP partials (the 1.07 GB streaming read, contiguous per block)
    k_gemv<<<dim3(64, PGV), 256, 0, stream>>>(p, cW, P);
    // reduce + relu + GIN-1 aggregate
    k_h1<<<256, 256, 0, stream>>>(P, cb, H1);
    // GIN 1
    k_gemm<<<dim3(32, PGM), 256, 0, stream>>>(H1, W1a, P);
    k_act<<<256, 256, 0, stream>>>(P, b1a, T1);
    k_gemm<<<dim3(32, PGM), 256, 0, stream>>>(T1, W1b, P);
    // relu + BN1 + GIN-2 aggregate
    k_bnh<<<256, 256, 0, stream>>>(P, b1b, g1, be1, H2);
    // GIN 2
    k_gemm<<<dim3(32, PGM), 256, 0, stream>>>(H2, W2a, P);
    k_act<<<256, 256, 0, stream>>>(P, b2a, T2);
    k_gemm<<<dim3(32, PGM), 256, 0, stream>>>(T2, W2b, P);
    // relu + BN2 -> output
    k_bn_out<<<256, 256, 0, stream>>>(P, b2b, g2, be2, out);
}

// Round 10
// 243.770 us; speedup vs baseline: 2.2522x; 1.0403x over previous
//
#include <hip/hip_runtime.h>
#include <hip/hip_bf16.h>

#define F_ 2048
#define C_ 64
#define NE (C_ * F_)   // 131072 elements per [64,2048] activation
#define PGV 8          // gemv partials (f-chunk = 256, 2 MB contiguous/block)
#define PGM 16         // gemm partials (k-chunk = 128, two-stage + prefetch)

typedef __attribute__((ext_vector_type(4))) float f32x4;

// ---------------------------------------------------------------------------
// Kernel 1: P[fc][c][o] = sum_{f in chunk fc} p[f] * W[c,f,o]   (f32)
// grid (64 c, 8 f-chunks) = 512 blocks; each block streams a CONTIGUOUS
// 2 MB of W via nontemporal loads (read-once data, don't pollute L2).
// ---------------------------------------------------------------------------
__global__ __launch_bounds__(256) void k_gemv(const float* __restrict__ p,
                                              const float* __restrict__ W,
                                              float* __restrict__ P0) {
    __shared__ float lp[256];
    const int c  = blockIdx.x;
    const int fc = blockIdx.y;
    const int t  = threadIdx.x;
    const int f0 = fc * 256;
    lp[t] = p[f0 + t];
    __syncthreads();

    const float* Wp = W + ((size_t)c << 22) + (size_t)f0 * F_;
    f32x4 aL = (f32x4)(0.f);
    f32x4 aH = (f32x4)(0.f);
#pragma unroll 4
    for (int ff = 0; ff < 256; ++ff) {
        float pv = lp[ff];
        f32x4 wl = __builtin_nontemporal_load((const f32x4*)(Wp + (size_t)ff * F_ + t * 4));
        f32x4 wh = __builtin_nontemporal_load((const f32x4*)(Wp + (size_t)ff * F_ + 1024 + t * 4));
        aL += pv * wl;
        aH += pv * wh;
    }
    float* dst = P0 + (size_t)fc * NE + c * F_;
    *(f32x4*)(dst + t * 4) = aL;
    *(f32x4*)(dst + 1024 + t * 4) = aH;
}

// ---------------------------------------------------------------------------
// Kernel 2: reduce 8 gemv partials + child_b -> relu -> GIN-1 agg -> H1 (f32)
// Block owns [64 c][8 o]; grid 256. Thread: c=t>>2, 2 o.
// ---------------------------------------------------------------------------
__global__ __launch_bounds__(256) void k_h1(const float* __restrict__ P0,
                                            const float* __restrict__ cb,
                                            float* __restrict__ H1) {
    __shared__ float xs[64 * 10];
    __shared__ float gs[32];
    __shared__ float aggL[8];
    const int t  = threadIdx.x;
    const int o0 = blockIdx.x * 8;
    const int c  = t >> 2;
    const int j  = (t & 3) * 2;

    float2 x = *(const float2*)(cb + c * F_ + o0 + j);
#pragma unroll
    for (int ps = 0; ps < PGV; ++ps) {
        float2 v = *(const float2*)(P0 + (size_t)ps * NE + c * F_ + o0 + j);
        x.x += v.x; x.y += v.y;
    }
    x.x = fmaxf(x.x, 0.f); x.y = fmaxf(x.y, 0.f);
    xs[c * 10 + j + 0] = x.x;
    xs[c * 10 + j + 1] = x.y;
    __syncthreads();

    if (t < 32) {                    // stage 1: 4 groups of 16 c
        const int o = t & 7, cg = t >> 3;
        float s = 0.f;
#pragma unroll
        for (int i = 0; i < 16; ++i) s += xs[(cg * 16 + i) * 10 + o];
        gs[cg * 8 + o] = s;
    }
    __syncthreads();
    if (t < 8) aggL[t] = gs[t] + gs[8 + t] + gs[16 + t] + gs[24 + t];
    __syncthreads();

    float2 r = x;
    if (c > 0) { r.x += aggL[j]; r.y += aggL[j + 1]; }
    *(float2*)(H1 + c * F_ + o0 + j) = r;
}

// ---------------------------------------------------------------------------
// Kernel 3: f32 GEMM partials, 4x4 micro-tile, two-stage k-chunk of 128 with
// ASYNC-STAGE PREFETCH: half-1 global loads are issued into registers before
// half-0's compute (HBM latency hides under the FMA burst), ds_write after
// the barrier. grid (32 n-tiles of 64, 16 k-chunks) = 512 blocks (2/CU).
// ---------------------------------------------------------------------------
__global__ __launch_bounds__(256) void k_gemm(const float* __restrict__ Hm,
                                              const float* __restrict__ W,
                                              float* __restrict__ P) {
    __shared__ float Ht[64 * 68];   // [k][m]
    __shared__ float Ws[64 * 68];   // [k][n]
    const int n0 = blockIdx.x * 64;
    const int k0 = blockIdx.y * 128;
    const int t  = threadIdx.x;
    const int tm4 = (t >> 4) * 4;   // 16 m-groups of 4 rows
    const int tn4 = (t & 15) * 4;   // 16 n-groups of 4 cols

    // --- load half-0 into regs, write to LDS ---
    float4 h0[4]; f32x4 w0[4];
#pragma unroll
    for (int it = 0; it < 4; ++it) {
        int s = t + it * 256;
        h0[it] = *(const float4*)&Hm[(s >> 4) * F_ + k0 + (s & 15) * 4];
        w0[it] = __builtin_nontemporal_load(
            (const f32x4*)&W[(size_t)(k0 + (s >> 4)) * F_ + n0 + (s & 15) * 4]);
    }
#pragma unroll
    for (int it = 0; it < 4; ++it) {
        int s = t + it * 256;
        int m = s >> 4, k4 = (s & 15) * 4;
        Ht[(k4 + 0) * 68 + m] = h0[it].x;
        Ht[(k4 + 1) * 68 + m] = h0[it].y;
        Ht[(k4 + 2) * 68 + m] = h0[it].z;
        Ht[(k4 + 3) * 68 + m] = h0[it].w;
        *(f32x4*)&Ws[(s >> 4) * 68 + (s & 15) * 4] = w0[it];
    }
    __syncthreads();

    // --- prefetch half-1 into regs (in flight during half-0 compute) ---
    float4 h1[4]; f32x4 w1[4];
#pragma unroll
    for (int it = 0; it < 4; ++it) {
        int s = t + it * 256;
        h1[it] = *(const float4*)&Hm[(s >> 4) * F_ + k0 + 64 + (s & 15) * 4];
        w1[it] = __builtin_nontemporal_load(
            (const f32x4*)&W[(size_t)(k0 + 64 + (s >> 4)) * F_ + n0 + (s & 15) * 4]);
    }

    f32x4 acc0 = (f32x4)(0.f), acc1 = (f32x4)(0.f);
    f32x4 acc2 = (f32x4)(0.f), acc3 = (f32x4)(0.f);

#pragma unroll 4
    for (int k = 0; k < 64; ++k) {              // compute half-0
        f32x4 a = *(const f32x4*)&Ht[k * 68 + tm4];
        f32x4 b = *(const f32x4*)&Ws[k * 68 + tn4];
        acc0 += a.x * b;
        acc1 += a.y * b;
        acc2 += a.z * b;
        acc3 += a.w * b;
    }
    __syncthreads();                            // done reading half-0 LDS

#pragma unroll
    for (int it = 0; it < 4; ++it) {            // write half-1 to LDS
        int s = t + it * 256;
        int m = s >> 4, k4 = (s & 15) * 4;
        Ht[(k4 + 0) * 68 + m] = h1[it].x;
        Ht[(k4 + 1) * 68 + m] = h1[it].y;
        Ht[(k4 + 2) * 68 + m] = h1[it].z;
        Ht[(k4 + 3) * 68 + m] = h1[it].w;
        *(f32x4*)&Ws[(s >> 4) * 68 + (s & 15) * 4] = w1[it];
    }
    __syncthreads();

#pragma unroll 4
    for (int k = 0; k < 64; ++k) {              // compute half-1
        f32x4 a = *(const f32x4*)&Ht[k * 68 + tm4];
        f32x4 b = *(const f32x4*)&Ws[k * 68 + tn4];
        acc0 += a.x * b;
        acc1 += a.y * b;
        acc2 += a.z * b;
        acc3 += a.w * b;
    }

    float* dst = P + (size_t)blockIdx.y * NE + n0 + tn4;
    *(f32x4*)&dst[(tm4 + 0) * F_] = acc0;
    *(f32x4*)&dst[(tm4 + 1) * F_] = acc1;
    *(f32x4*)&dst[(tm4 + 2) * F_] = acc2;
    *(f32x4*)&dst[(tm4 + 3) * F_] = acc3;
}

// ---------------------------------------------------------------------------
// Kernel 4: T = relu(sum_p P[p] + bias[o])  (f32), float2, grid 256.
// ---------------------------------------------------------------------------
__global__ __launch_bounds__(256) void k_act(const float* __restrict__ P,
                                             const float* __restrict__ b,
                                             float* __restrict__ T) {
    const int e = (blockIdx.x * 256 + threadIdx.x) * 2;
    const int o = e & (F_ - 1);
    float2 a = *(const float2*)(b + o);
#pragma unroll 8
    for (int ps = 0; ps < PGM; ++ps) {
        float2 v = *(const float2*)(P + (size_t)ps * NE + e);
        a.x += v.x; a.y += v.y;
    }
    a.x = fmaxf(a.x, 0.f); a.y = fmaxf(a.y, 0.f);
    *(float2*)(T + e) = a;
}

// ---------------------------------------------------------------------------
// Kernel 5: reduce partials + bias -> relu -> BatchNorm -> (+ GIN-2 agg) -> H
// Block owns [64 c][8 o]; grid 256. sum_c(BN(x)) == 64*beta exactly.
// ---------------------------------------------------------------------------
__global__ __launch_bounds__(256) void k_bnh(const float* __restrict__ P,
                                             const float* __restrict__ bias,
                                             const float* __restrict__ g,
                                             const float* __restrict__ beta,
                                             float* __restrict__ H) {
    __shared__ float xs[64 * 10];
    __shared__ float gs[32];
    __shared__ float gs2[32];
    __shared__ float mL[8];
    __shared__ float rL[8];
    const int t  = threadIdx.x;
    const int o0 = blockIdx.x * 8;
    const int c  = t >> 2;
    const int j  = (t & 3) * 2;

    float2 x = *(const float2*)(bias + o0 + j);
#pragma unroll 8
    for (int ps = 0; ps < PGM; ++ps) {
        float2 v = *(const float2*)(P + (size_t)ps * NE + c * F_ + o0 + j);
        x.x += v.x; x.y += v.y;
    }
    x.x = fmaxf(x.x, 0.f); x.y = fmaxf(x.y, 0.f);
    xs[c * 10 + j + 0] = x.x;
    xs[c * 10 + j + 1] = x.y;
    __syncthreads();

    if (t < 32) {
        const int o = t & 7, cg = t >> 3;
        float s = 0.f, s2 = 0.f;
#pragma unroll
        for (int i = 0; i < 16; ++i) {
            float v = xs[(cg * 16 + i) * 10 + o];
            s += v; s2 += v * v;
        }
        gs[cg * 8 + o] = s;
        gs2[cg * 8 + o] = s2;
    }
    __syncthreads();
    if (t < 8) {
        float s  = gs[t] + gs[8 + t] + gs[16 + t] + gs[24 + t];
        float s2 = gs2[t] + gs2[8 + t] + gs2[16 + t] + gs2[24 + t];
        float m   = s * (1.f / C_);
        float var = s2 * (1.f / C_) - m * m;
        mL[t] = m;
        rL[t] = 1.f / sqrtf(var + 1e-5f);
    }
    __syncthreads();

    float2 g2v = *(const float2*)(g + o0 + j);
    float2 b2v = *(const float2*)(beta + o0 + j);
    float2 r;
    r.x = (x.x - mL[j + 0]) * rL[j + 0] * g2v.x + b2v.x;
    r.y = (x.y - mL[j + 1]) * rL[j + 1] * g2v.y + b2v.y;
    if (c > 0) {   // GIN-2 aggregate: sum_c xn = 64*beta exactly
        r.x += C_ * b2v.x;
        r.y += C_ * b2v.y;
    }
    *(float2*)(H + c * F_ + o0 + j) = r;
}

// ---------------------------------------------------------------------------
// Kernel 6: reduce partials + bias -> relu -> BatchNorm -> out (f32, no agg).
// Block owns [64 c][8 o]; grid 256.
// ---------------------------------------------------------------------------
__global__ __launch_bounds__(256) void k_bn_out(const float* __restrict__ P,
                                                const float* __restrict__ bias,
                                                const float* __restrict__ g,
                                                const float* __restrict__ beta,
                                                float* __restrict__ out) {
    __shared__ float xs[64 * 10];
    __shared__ float gs[32];
    __shared__ float gs2[32];
    __shared__ float mL[8];
    __shared__ float rL[8];
    const int t  = threadIdx.x;
    const int o0 = blockIdx.x * 8;
    const int c  = t >> 2;
    const int j  = (t & 3) * 2;

    float2 x = *(const float2*)(bias + o0 + j);
#pragma unroll 8
    for (int ps = 0; ps < PGM; ++ps) {
        float2 v = *(const float2*)(P + (size_t)ps * NE + c * F_ + o0 + j);
        x.x += v.x; x.y += v.y;
    }
    x.x = fmaxf(x.x, 0.f); x.y = fmaxf(x.y, 0.f);
    xs[c * 10 + j + 0] = x.x;
    xs[c * 10 + j + 1] = x.y;
    __syncthreads();

    if (t < 32) {
        const int o = t & 7, cg = t >> 3;
        float s = 0.f, s2 = 0.f;
#pragma unroll
        for (int i = 0; i < 16; ++i) {
            float v = xs[(cg * 16 + i) * 10 + o];
            s += v; s2 += v * v;
        }
        gs[cg * 8 + o] = s;
        gs2[cg * 8 + o] = s2;
    }
    __syncthreads();
    if (t < 8) {
        float s  = gs[t] + gs[8 + t] + gs[16 + t] + gs[24 + t];
        float s2 = gs2[t] + gs2[8 + t] + gs2[16 + t] + gs2[24 + t];
        float m   = s * (1.f / C_);
        float var = s2 * (1.f / C_) - m * m;
        mL[t] = m;
        rL[t] = 1.f / sqrtf(var + 1e-5f);
    }
    __syncthreads();

    float2 g2v = *(const float2*)(g + o0 + j);
    float2 b2v = *(const float2*)(beta + o0 + j);
    float2 r;
    r.x = (x.x - mL[j + 0]) * rL[j + 0] * g2v.x + b2v.x;
    r.y = (x.y - mL[j + 1]) * rL[j + 1] * g2v.y + b2v.y;
    *(float2*)(out + c * F_ + o0 + j) = r;
}

extern "C" void kernel_launch(void* const* d_in, const int* in_sizes, int n_in,
                              void* d_out, int out_size, void* d_ws, size_t ws_size,
                              hipStream_t stream) {
    const float* p   = (const float*)d_in[0];
    const float* cW  = (const float*)d_in[1];
    const float* cb  = (const float*)d_in[2];
    const float* W1a = (const float*)d_in[3];
    const float* b1a = (const float*)d_in[4];
    const float* W1b = (const float*)d_in[5];
    const float* b1b = (const float*)d_in[6];
    const float* g1  = (const float*)d_in[7];
    const float* be1 = (const float*)d_in[8];
    const float* W2a = (const float*)d_in[9];
    const float* b2a = (const float*)d_in[10];
    const float* W2b = (const float*)d_in[11];
    const float* b2b = (const float*)d_in[12];
    const float* g2  = (const float*)d_in[13];
    const float* be2 = (const float*)d_in[14];
    float* out = (float*)d_out;
    float* ws  = (float*)d_ws;

    // Partial buffer P [16][64][2048] f32 (8.4 MB): gemv uses slots 0..7,
    // each GEMM uses slots 0..15; reuse serialized by stream order.
    float* P  = ws;
    float* H1 = ws + (size_t)16 * NE;
    float* T1 = H1 + NE;
    float* H2 = T1 + NE;
    float* T2 = H2 + NE;

    // child MLP partials (the 1.07 GB streaming read, contiguous per block)
    k_gemv<<<dim3(64, PGV), 256, 0, stream>>>(p, cW, P);
    // reduce + relu + GIN-1 aggregate
    k_h1<<<256, 256, 0, stream>>>(P, cb, H1);
    // GIN 1
    k_gemm<<<dim3(32, PGM), 256, 0, stream>>>(H1, W1a, P);
    k_act<<<256, 256, 0, stream>>>(P, b1a, T1);
    k_gemm<<<dim3(32, PGM), 256, 0, stream>>>(T1, W1b, P);
    // relu + BN1 + GIN-2 aggregate
    k_bnh<<<256, 256, 0, stream>>>(P, b1b, g1, be1, H2);
    // GIN 2
    k_gemm<<<dim3(32, PGM), 256, 0, stream>>>(H2, W2a, P);
    k_act<<<256, 256, 0, stream>>>(P, b2a, T2);
    k_gemm<<<dim3(32, PGM), 256, 0, stream>>>(T2, W2b, P);
    // relu + BN2 -> output
    k_bn_out<<<256, 256, 0, stream>>>(P, b2b, g2, be2, out);
}